// Round 1
// 2076.611 us; speedup vs baseline: 2.1404x; 2.1404x over previous
//
#include <hip/hip_runtime.h>
#include <hip/hip_bf16.h>
#include <stdint.h>

#define B 2
#define N 1024
#define DIM 1024
#define HEADS 16
#define HD 64
#define E3 (3*DIM)
#define M (B*N)

typedef __hip_bfloat16 bf16;
typedef __attribute__((ext_vector_type(8))) short short8v;
typedef __attribute__((ext_vector_type(4))) float f32x4;

__device__ __forceinline__ float scrub(float v) {
    return (v == v && fabsf(v) < 1e30f) ? v : 0.0f;
}
__device__ __forceinline__ float b2f(bf16 x) { return scrub(__bfloat162float(x)); }

template<bool FP32>
__device__ __forceinline__ float ldin(const void* p, int i) {
    if (FP32) return scrub(((const float*)p)[i]);
    else      return scrub(__bfloat162float(((const bf16*)p)[i]));
}

__device__ __forceinline__ bool sniff_fp32(const void* x, int tid, int* sbad) {
    if (tid == 0) *sbad = 0;
    __syncthreads();
    if (tid < 64) {
        const unsigned short* u = (const unsigned short*)x;
        int ex = (u[tid] >> 7) & 0xFF;
        if (ex == 0xFF || ex >= 135 || (ex != 0 && ex <= 118))
            atomicAdd(sbad, 1);
    }
    __syncthreads();
    return *sbad > 4;
}

// ---------------- Kernel 1: complex QKV projection, 32x32 tile / 2x2 per thread ----------------
// C[row,e] = sum_k x[row,k]*Wqkv[e,k] + b (complex); scatter q/k/v + rotary.
// V is written TRANSPOSED per head: [b,h,d,n] so attention PV reads are contiguous.
template<bool FP32>
__device__ void qkv_body2(
    const void* xr, const void* xi, const void* fr_, const void* fi_,
    const void* Wr, const void* Wi, const void* br, const void* bi,
    bf16* qr, bf16* qi, bf16* kr, bf16* ki, bf16* vr, bf16* vi,
    float (*sxr)[33], float (*sxi)[33], float (*swr)[33], float (*swi)[33])
{
    int tx = threadIdx.x, ty = threadIdx.y;
    int row0 = blockIdx.y*32, col0 = blockIdx.x*32;
    float accr[2][2] = {}, acci[2][2] = {};

    for (int k0 = 0; k0 < DIM; k0 += 16) {
        sxr[ty][tx]    = ldin<FP32>(xr, (row0+ty)*DIM    + k0 + tx);
        sxr[ty+16][tx] = ldin<FP32>(xr, (row0+ty+16)*DIM + k0 + tx);
        sxi[ty][tx]    = ldin<FP32>(xi, (row0+ty)*DIM    + k0 + tx);
        sxi[ty+16][tx] = ldin<FP32>(xi, (row0+ty+16)*DIM + k0 + tx);
        swr[ty][tx]    = ldin<FP32>(Wr, (col0+ty)*DIM    + k0 + tx);
        swr[ty+16][tx] = ldin<FP32>(Wr, (col0+ty+16)*DIM + k0 + tx);
        swi[ty][tx]    = ldin<FP32>(Wi, (col0+ty)*DIM    + k0 + tx);
        swi[ty+16][tx] = ldin<FP32>(Wi, (col0+ty+16)*DIM + k0 + tx);
        __syncthreads();
        #pragma unroll
        for (int kk = 0; kk < 16; ++kk) {
            float ar0 = sxr[ty][kk],    ai0 = sxi[ty][kk];
            float ar1 = sxr[ty+16][kk], ai1 = sxi[ty+16][kk];
            float wr0 = swr[tx][kk],    wi0 = swi[tx][kk];
            float wr1 = swr[tx+16][kk], wi1 = swi[tx+16][kk];
            accr[0][0] += ar0*wr0 - ai0*wi0;  acci[0][0] += ar0*wi0 + ai0*wr0;
            accr[0][1] += ar0*wr1 - ai0*wi1;  acci[0][1] += ar0*wi1 + ai0*wr1;
            accr[1][0] += ar1*wr0 - ai1*wi0;  acci[1][0] += ar1*wi0 + ai1*wr0;
            accr[1][1] += ar1*wr1 - ai1*wi1;  acci[1][1] += ar1*wi1 + ai1*wr1;
        }
        __syncthreads();
    }

    #pragma unroll
    for (int i = 0; i < 2; ++i)
    #pragma unroll
    for (int j = 0; j < 2; ++j) {
        int row = row0 + ty + 16*i;
        int col = col0 + tx + 16*j;
        float cr = accr[i][j] + ldin<FP32>(br, col);
        float ci = acci[i][j] + ldin<FP32>(bi, col);

        int s = col % 3;
        int t = col / 3;
        int h = t / HD, d = t % HD;
        int b = row / N, n = row % N;
        if (s == 2) {
            // transposed V layout: [b,h,d,n]
            int idxT = ((b*HEADS + h)*HD + d)*N + n;
            vr[idxT] = __float2bfloat16(scrub(cr));
            vi[idxT] = __float2bfloat16(scrub(ci));
        } else {
            int idx = ((b*HEADS + h)*N + n)*HD + d;
            float fre = ldin<FP32>(fr_, n*HD + d), fim = ldin<FP32>(fi_, n*HD + d);
            float rr = cr*fre - ci*fim;
            float ri = cr*fim + ci*fre;
            if (s == 0) { qr[idx] = __float2bfloat16(scrub(rr)); qi[idx] = __float2bfloat16(scrub(ri)); }
            else        { kr[idx] = __float2bfloat16(scrub(rr)); ki[idx] = __float2bfloat16(scrub(ri)); }
        }
    }
}

__global__ __launch_bounds__(256) void qkv_kernel(
    const void* xr, const void* xi, const void* fr_, const void* fi_,
    const void* Wr, const void* Wi, const void* br, const void* bi,
    bf16* qr, bf16* qi, bf16* kr, bf16* ki, bf16* vr, bf16* vi)
{
    __shared__ float sxr[32][33], sxi[32][33], swr[32][33], swi[32][33];
    __shared__ int sbad;
    int tid = threadIdx.y*16 + threadIdx.x;
    bool f32 = sniff_fp32(xr, tid, &sbad);
    if (f32) qkv_body2<true >(xr,xi,fr_,fi_,Wr,Wi,br,bi,qr,qi,kr,ki,vr,vi,sxr,sxi,swr,swi);
    else     qkv_body2<false>(xr,xi,fr_,fi_,Wr,Wi,br,bi,qr,qi,kr,ki,vr,vi,sxr,sxi,swr,swi);
}

// ---------------- Kernel 2: flash-style MFMA attention ----------------
// Block = 4 waves = 64 q-rows of one (b,h). 16 KV tiles of 64 rows.
// LDS tiles are stored with chunk-XOR swizzle: 16B chunk j of row r lives at
// physical chunk (j ^ (r&7)). Applied on BOTH the staging source permutation
// and the fragment reads, so b128 reads land 8 lanes per 4-bank stripe (balanced).

__device__ __forceinline__ short8v frag_ld(const bf16* base, int row, int j) {
    return *(const short8v*)(base + row*64 + ((j ^ (row & 7)) << 3));
}
__device__ __forceinline__ f32x4 mfma16(short8v a, short8v b, f32x4 c) {
    return __builtin_amdgcn_mfma_f32_16x16x32_bf16(a, b, c, 0, 0, 0);
}

__global__ __launch_bounds__(256) void attn_kernel(
    const bf16* qr, const bf16* qi, const bf16* kr, const bf16* ki,
    const bf16* vtr, const bf16* vti, bf16* aor_, bf16* aoi_)
{
    __shared__ __align__(16) bf16 skr[64*64];
    __shared__ __align__(16) bf16 ski[64*64];
    __shared__ __align__(16) bf16 svr[64*64];   // Vt tile: [d][m]
    __shared__ __align__(16) bf16 svi[64*64];
    __shared__ __align__(16) bf16 sp[4][16*64]; // per-wave P tile

    const int t  = threadIdx.x;
    const int w  = t >> 6;        // wave 0..3
    const int l  = t & 63;
    const int lr = l & 15;        // lane row/col component
    const int lg = l >> 4;        // lane k-group 0..3
    const int qt = blockIdx.x & 15;
    const int bh = blockIdx.x >> 4;

    const size_t hbase = (size_t)bh * N * HD;

    // ---- Q fragments in registers (A-operand: row = lr, k = 32*ks + 8*lg + e) ----
    const bf16* qrg = qr + hbase + (size_t)(qt*64 + w*16 + lr) * HD;
    const bf16* qig = qi + hbase + (size_t)(qt*64 + w*16 + lr) * HD;
    short8v qfr[2], qfi[2], qfrn[2];
    #pragma unroll
    for (int ks = 0; ks < 2; ++ks) {
        qfr[ks] = *(const short8v*)(qrg + 32*ks + 8*lg);
        qfi[ks] = *(const short8v*)(qig + 32*ks + 8*lg);
        #pragma unroll
        for (int e = 0; e < 8; ++e)
            qfrn[ks][e] = (short)(qfr[ks][e] ^ (short)0x8000);   // -Qr
    }

    // ---- staging: thread covers chunks t and t+256 of each 512-chunk plane ----
    const int cA = t, cB = t + 256;
    const int rA = cA >> 3, jA = (cA & 7) ^ (rA & 7);
    const int rB = cB >> 3, jB = (cB & 7) ^ (rB & 7);
    const bf16* krg = kr  + hbase;
    const bf16* kig = ki  + hbase;
    const bf16* vrg = vtr + hbase;   // [d][n]
    const bf16* vig = vti + hbase;

    f32x4 outr[4], outi[4];
    #pragma unroll
    for (int dt = 0; dt < 4; ++dt) {
        outr[dt] = (f32x4){0.f,0.f,0.f,0.f};
        outi[dt] = (f32x4){0.f,0.f,0.f,0.f};
    }
    float mrow[4] = {-1e30f,-1e30f,-1e30f,-1e30f};
    float lrow[4] = {0.f,0.f,0.f,0.f};

    for (int kt = 0; kt < N/64; ++kt) {
        const int m0 = kt*64;
        // stage K[m][d] and Vt[d][m] tiles, pre-permuted source -> swizzled LDS
        *(short8v*)(skr + cA*8) = *(const short8v*)(krg + (size_t)(m0+rA)*HD + jA*8);
        *(short8v*)(skr + cB*8) = *(const short8v*)(krg + (size_t)(m0+rB)*HD + jB*8);
        *(short8v*)(ski + cA*8) = *(const short8v*)(kig + (size_t)(m0+rA)*HD + jA*8);
        *(short8v*)(ski + cB*8) = *(const short8v*)(kig + (size_t)(m0+rB)*HD + jB*8);
        *(short8v*)(svr + cA*8) = *(const short8v*)(vrg + (size_t)rA*N + m0 + jA*8);
        *(short8v*)(svr + cB*8) = *(const short8v*)(vrg + (size_t)rB*N + m0 + jB*8);
        *(short8v*)(svi + cA*8) = *(const short8v*)(vig + (size_t)rA*N + m0 + jA*8);
        *(short8v*)(svi + cB*8) = *(const short8v*)(vig + (size_t)rB*N + m0 + jB*8);
        __syncthreads();

        // S = Q conj(K)^T : Sr = Qr Kr^T + Qi Ki^T ; Si = Qi Kr^T - Qr Ki^T
        f32x4 sr[4], si[4];
        #pragma unroll
        for (int ct = 0; ct < 4; ++ct) {
            f32x4 ar = (f32x4){0.f,0.f,0.f,0.f};
            f32x4 ai = (f32x4){0.f,0.f,0.f,0.f};
            #pragma unroll
            for (int ks = 0; ks < 2; ++ks) {
                short8v kfr = frag_ld(skr, 16*ct + lr, 4*ks + lg);
                short8v kfi = frag_ld(ski, 16*ct + lr, 4*ks + lg);
                ar = mfma16(qfr[ks],  kfr, ar);
                ar = mfma16(qfi[ks],  kfi, ar);
                ai = mfma16(qfi[ks],  kfr, ai);
                ai = mfma16(qfrn[ks], kfi, ai);
            }
            sr[ct] = ar; si[ct] = ai;
        }

        // |S| * scale, online softmax (row = 4*lg + r, cols across lanes lr + ct)
        float p[4][4];
        float pmax[4] = {-1e30f,-1e30f,-1e30f,-1e30f};
        #pragma unroll
        for (int ct = 0; ct < 4; ++ct)
        #pragma unroll
        for (int r = 0; r < 4; ++r) {
            float s = sqrtf(sr[ct][r]*sr[ct][r] + si[ct][r]*si[ct][r]) * 0.125f;
            p[ct][r] = s;
            pmax[r] = fmaxf(pmax[r], s);
        }
        #pragma unroll
        for (int mk = 1; mk <= 8; mk <<= 1)
        #pragma unroll
        for (int r = 0; r < 4; ++r)
            pmax[r] = fmaxf(pmax[r], __shfl_xor(pmax[r], mk));

        float fsc[4];
        #pragma unroll
        for (int r = 0; r < 4; ++r) {
            float mnew = fmaxf(mrow[r], pmax[r]);
            fsc[r] = __expf(mrow[r] - mnew);
            mrow[r] = mnew;
        }
        float rsum[4] = {0.f,0.f,0.f,0.f};
        #pragma unroll
        for (int ct = 0; ct < 4; ++ct)
        #pragma unroll
        for (int r = 0; r < 4; ++r) {
            float e = __expf(p[ct][r] - mrow[r]);
            p[ct][r] = e;
            rsum[r] += e;
        }
        #pragma unroll
        for (int mk = 1; mk <= 8; mk <<= 1)
        #pragma unroll
        for (int r = 0; r < 4; ++r)
            rsum[r] += __shfl_xor(rsum[r], mk);
        #pragma unroll
        for (int r = 0; r < 4; ++r)
            lrow[r] = lrow[r]*fsc[r] + rsum[r];
        #pragma unroll
        for (int dt = 0; dt < 4; ++dt)
        #pragma unroll
        for (int r = 0; r < 4; ++r) {
            outr[dt][r] *= fsc[r];
            outi[dt][r] *= fsc[r];
        }

        // P (D-layout) -> per-wave LDS (swizzled) -> A-fragments
        bf16* pw = sp[w];
        #pragma unroll
        for (int ct = 0; ct < 4; ++ct)
        #pragma unroll
        for (int r = 0; r < 4; ++r) {
            int prow = 4*lg + r;
            int pcol = 16*ct + lr;
            int jj = (pcol >> 3) ^ (prow & 7);
            pw[prow*64 + jj*8 + (pcol & 7)] = __float2bfloat16(p[ct][r]);
        }
        short8v pa[2];
        #pragma unroll
        for (int ks2 = 0; ks2 < 2; ++ks2)
            pa[ks2] = frag_ld(pw, lr, 4*ks2 + lg);

        // out += P * V  (real P, complex V)
        #pragma unroll
        for (int dt = 0; dt < 4; ++dt)
        #pragma unroll
        for (int ks2 = 0; ks2 < 2; ++ks2) {
            short8v vfr = frag_ld(svr, 16*dt + lr, 4*ks2 + lg);
            short8v vfi = frag_ld(svi, 16*dt + lr, 4*ks2 + lg);
            outr[dt] = mfma16(pa[ks2], vfr, outr[dt]);
            outi[dt] = mfma16(pa[ks2], vfi, outi[dt]);
        }
        __syncthreads();
    }

    // epilogue: normalize and write [b, n, h*HD + d]
    const int b_ = bh / HEADS, h_ = bh % HEADS;
    float invl[4];
    #pragma unroll
    for (int r = 0; r < 4; ++r) invl[r] = 1.0f / lrow[r];
    #pragma unroll
    for (int dt = 0; dt < 4; ++dt)
    #pragma unroll
    for (int r = 0; r < 4; ++r) {
        int n_ = qt*64 + w*16 + 4*lg + r;
        int d_ = 16*dt + lr;
        size_t oidx = ((size_t)(b_*N + n_))*DIM + h_*HD + d_;
        aor_[oidx] = __float2bfloat16(scrub(outr[dt][r]*invl[r]));
        aoi_[oidx] = __float2bfloat16(scrub(outi[dt][r]*invl[r]));
    }
}

// ---------------- Kernel 3: complex out projection, 32x32 tile / 2x2 per thread ----------------
template<bool FP32>
__device__ void outproj_body2(
    const bf16* ar, const bf16* ai,
    const void* Wr, const void* Wi, const void* br, const void* bi,
    void* out,
    float (*sxr)[33], float (*sxi)[33], float (*swr)[33], float (*swi)[33])
{
    int tx = threadIdx.x, ty = threadIdx.y;
    int row0 = blockIdx.y*32, col0 = blockIdx.x*32;
    float accr[2][2] = {}, acci[2][2] = {};

    for (int k0 = 0; k0 < DIM; k0 += 16) {
        sxr[ty][tx]    = b2f(ar[(row0+ty)*DIM    + k0 + tx]);
        sxr[ty+16][tx] = b2f(ar[(row0+ty+16)*DIM + k0 + tx]);
        sxi[ty][tx]    = b2f(ai[(row0+ty)*DIM    + k0 + tx]);
        sxi[ty+16][tx] = b2f(ai[(row0+ty+16)*DIM + k0 + tx]);
        swr[ty][tx]    = ldin<FP32>(Wr, (col0+ty)*DIM    + k0 + tx);
        swr[ty+16][tx] = ldin<FP32>(Wr, (col0+ty+16)*DIM + k0 + tx);
        swi[ty][tx]    = ldin<FP32>(Wi, (col0+ty)*DIM    + k0 + tx);
        swi[ty+16][tx] = ldin<FP32>(Wi, (col0+ty+16)*DIM + k0 + tx);
        __syncthreads();
        #pragma unroll
        for (int kk = 0; kk < 16; ++kk) {
            float ar0 = sxr[ty][kk],    ai0 = sxi[ty][kk];
            float ar1 = sxr[ty+16][kk], ai1 = sxi[ty+16][kk];
            float wr0 = swr[tx][kk],    wi0 = swi[tx][kk];
            float wr1 = swr[tx+16][kk], wi1 = swi[tx+16][kk];
            accr[0][0] += ar0*wr0 - ai0*wi0;  acci[0][0] += ar0*wi0 + ai0*wr0;
            accr[0][1] += ar0*wr1 - ai0*wi1;  acci[0][1] += ar0*wi1 + ai0*wr1;
            accr[1][0] += ar1*wr0 - ai1*wi0;  acci[1][0] += ar1*wi0 + ai1*wr0;
            accr[1][1] += ar1*wr1 - ai1*wi1;  acci[1][1] += ar1*wi1 + ai1*wr1;
        }
        __syncthreads();
    }

    #pragma unroll
    for (int i = 0; i < 2; ++i)
    #pragma unroll
    for (int j = 0; j < 2; ++j) {
        int row = row0 + ty + 16*i;
        int col = col0 + tx + 16*j;
        float cr = scrub(accr[i][j] + ldin<FP32>(br, col));
        float ci = scrub(acci[i][j] + ldin<FP32>(bi, col));
        if (FP32) {
            ((float*)out)[row*DIM + col]         = cr;
            ((float*)out)[M*DIM + row*DIM + col] = ci;
        } else {
            ((bf16*)out)[row*DIM + col]          = __float2bfloat16(cr);
            ((bf16*)out)[M*DIM + row*DIM + col]  = __float2bfloat16(ci);
        }
    }
}

__global__ __launch_bounds__(256) void outproj_kernel(
    const void* xprobe,
    const bf16* ar, const bf16* ai,
    const void* Wr, const void* Wi, const void* br, const void* bi,
    void* out)
{
    __shared__ float sxr[32][33], sxi[32][33], swr[32][33], swi[32][33];
    __shared__ int sbad;
    int tid = threadIdx.y*16 + threadIdx.x;
    bool f32 = sniff_fp32(xprobe, tid, &sbad);
    if (f32) outproj_body2<true >(ar,ai,Wr,Wi,br,bi,out,sxr,sxi,swr,swi);
    else     outproj_body2<false>(ar,ai,Wr,Wi,br,bi,out,sxr,sxi,swr,swi);
}

extern "C" void kernel_launch(void* const* d_in, const int* in_sizes, int n_in,
                              void* d_out, int out_size, void* d_ws, size_t ws_size,
                              hipStream_t stream)
{
    const void* xr     = d_in[0];
    const void* xi     = d_in[1];
    const void* fr     = d_in[2];
    const void* fi     = d_in[3];
    const void* Wqkv_r = d_in[4];
    const void* Wqkv_i = d_in[5];
    const void* bqkv_r = d_in[6];
    const void* bqkv_i = d_in[7];
    const void* Wout_r = d_in[8];
    const void* Wout_i = d_in[9];
    const void* bout_r = d_in[10];
    const void* bout_i = d_in[11];

    // ws layout: 8 bf16 planes of QS elements = 32 MiB total
    bf16* w = (bf16*)d_ws;
    const size_t QS = (size_t)B*HEADS*N*HD;   // 2,097,152
    bf16* qr   = w;          bf16* qi   = qr  + QS;
    bf16* kr   = qi  + QS;   bf16* ki   = kr  + QS;
    bf16* vr   = ki  + QS;   bf16* vi   = vr  + QS;   // TRANSPOSED [b,h,d,n]
    bf16* aor_ = vi  + QS;   bf16* aoi_ = aor_ + QS;

    dim3 blk(16, 16);
    qkv_kernel<<<dim3(E3/32, M/32), blk, 0, stream>>>(
        xr, xi, fr, fi, Wqkv_r, Wqkv_i, bqkv_r, bqkv_i, qr, qi, kr, ki, vr, vi);

    attn_kernel<<<dim3(B*HEADS*(N/64)), dim3(256), 0, stream>>>(
        qr, qi, kr, ki, vr, vi, aor_, aoi_);

    outproj_kernel<<<dim3(DIM/32, M/32), blk, 0, stream>>>(
        xr, aor_, aoi_, Wout_r, Wout_i, bout_r, bout_i, d_out);
}

// Round 3
// 404.716 us; speedup vs baseline: 10.9826x; 5.1310x over previous
//
#include <hip/hip_runtime.h>
#include <hip/hip_bf16.h>
#include <stdint.h>

#define B 2
#define N 1024
#define DIM 1024
#define HEADS 16
#define HD 64
#define E3 (3*DIM)
#define M (B*N)

typedef __hip_bfloat16 bf16;
typedef __attribute__((ext_vector_type(8))) short short8v;
typedef __attribute__((ext_vector_type(4))) float f32x4;
typedef __attribute__((ext_vector_type(4))) unsigned int u32x4;

__device__ __forceinline__ float scrub(float v) {
    return (v == v && fabsf(v) < 1e30f) ? v : 0.0f;
}
__device__ __forceinline__ float b2f(bf16 x) { return scrub(__bfloat162float(x)); }

template<bool FP32>
__device__ __forceinline__ float ldin(const void* p, int i) {
    if (FP32) return scrub(((const float*)p)[i]);
    else      return scrub(__bfloat162float(((const bf16*)p)[i]));
}

__device__ __forceinline__ bool sniff_fp32(const void* x, int tid, int* sbad) {
    if (tid == 0) *sbad = 0;
    __syncthreads();
    if (tid < 64) {
        const unsigned short* u = (const unsigned short*)x;
        int ex = (u[tid] >> 7) & 0xFF;
        if (ex == 0xFF || ex >= 135 || (ex != 0 && ex <= 118))
            atomicAdd(sbad, 1);
    }
    __syncthreads();
    return *sbad > 4;
}

__device__ __forceinline__ short f2bs(float x) {
    bf16 h = __float2bfloat16(x);
    return __builtin_bit_cast(short, h);
}

// LDS tiles: rows of 64 bf16 (128 B). 16B chunk j of row r lives at physical
// chunk (j ^ (r&7)) — involution applied at both staging-source and reads.
// Measured ZERO bank conflicts in the attn kernel (R1).
__device__ __forceinline__ short8v frag_ld(const bf16* base, int row, int j) {
    return *(const short8v*)(base + row*64 + ((j ^ (row & 7)) << 3));
}
__device__ __forceinline__ f32x4 mfma16(short8v a, short8v b, f32x4 c) {
    return __builtin_amdgcn_mfma_f32_16x16x32_bf16(a, b, c, 0, 0, 0);
}
__device__ __forceinline__ short8v neg8(short8v x) {   // flip bf16 sign bits
    u32x4 u = __builtin_bit_cast(u32x4, x);
    u ^= 0x80008000u;
    return __builtin_bit_cast(short8v, u);
}

// stage one 16B chunk (8 bf16) into LDS; SPLIT: also write bf16 residual (hi+lo split)
template<bool FP32, bool SPLIT>
__device__ __forceinline__ void stage8s(bf16* dhi, bf16* dlo, const void* src, size_t off) {
    if constexpr (FP32) {
        const float* s = (const float*)src + off;
        float4 a = *(const float4*)s;
        float4 b = *(const float4*)(s + 4);
        float v[8] = {a.x,a.y,a.z,a.w,b.x,b.y,b.z,b.w};
        short8v hi, lo;
        #pragma unroll
        for (int e = 0; e < 8; ++e) {
            float f = scrub(v[e]);
            bf16 h = __float2bfloat16(f);
            hi[e] = __builtin_bit_cast(short, h);
            if constexpr (SPLIT)
                lo[e] = f2bs(f - __bfloat162float(h));
        }
        *(short8v*)dhi = hi;
        if constexpr (SPLIT) *(short8v*)dlo = lo;
    } else {
        *(short8v*)dhi = *(const short8v*)((const bf16*)src + off);
        // bf16 input: value is exact in hi; lo plane unused (SPLIT only with FP32)
        (void)dlo;
    }
}

// ---------------- complex bf16 MFMA GEMM core, split-precision capable ----------------
// C[row,col] = sum_k A[row,k] * W[col,k]  (complex). Tile 64x64, BK=64.
// 4 waves in 2x2; each wave owns 32x32 = 2x2 fragments of 16x16.
// SPLIT_A/SPLIT_W: operand = hi + lo bf16 planes (lo*lo dropped, ~2^-18 rel).
template<bool AFP32, bool WFP32, bool SPLIT_A, bool SPLIT_W>
__device__ __forceinline__ void cgemm_core64(
    const void* Apr, const void* Api, const void* Bpr, const void* Bpi,
    int row0, int col0,
    bf16* sArh, bf16* sAih, bf16* sArl, bf16* sAil,
    bf16* sBrh, bf16* sBih, bf16* sBrl, bf16* sBil,
    f32x4 (*accr)[2], f32x4 (*acci)[2])
{
    const int t  = threadIdx.x;
    const int w  = t >> 6, l = t & 63;
    const int lr = l & 15, lg = l >> 4;
    const int wm = w >> 1, wn = w & 1;

    for (int k0 = 0; k0 < DIM; k0 += 64) {
        #pragma unroll
        for (int u = 0; u < 2; ++u) {
            int c = t + 256*u;
            int rrow = c >> 3;
            int j = (c & 7) ^ (rrow & 7);
            size_t offA = (size_t)(row0 + rrow)*DIM + k0 + j*8;
            size_t offB = (size_t)(col0 + rrow)*DIM + k0 + j*8;
            stage8s<AFP32, SPLIT_A>(sArh + c*8, sArl + c*8, Apr, offA);
            stage8s<AFP32, SPLIT_A>(sAih + c*8, sAil + c*8, Api, offA);
            stage8s<WFP32, SPLIT_W>(sBrh + c*8, sBrl + c*8, Bpr, offB);
            stage8s<WFP32, SPLIT_W>(sBih + c*8, sBil + c*8, Bpi, offB);
        }
        __syncthreads();

        #pragma unroll
        for (int ks = 0; ks < 2; ++ks) {
            short8v arh[2], aih[2], aihn[2];
            short8v arl[2], ail[2], ailn[2];
            #pragma unroll
            for (int mi = 0; mi < 2; ++mi) {
                int arow = wm*32 + mi*16 + lr;
                arh[mi] = frag_ld(sArh, arow, 4*ks + lg);
                aih[mi] = frag_ld(sAih, arow, 4*ks + lg);
                aihn[mi] = neg8(aih[mi]);
                if constexpr (SPLIT_A) {
                    arl[mi] = frag_ld(sArl, arow, 4*ks + lg);
                    ail[mi] = frag_ld(sAil, arow, 4*ks + lg);
                    ailn[mi] = neg8(ail[mi]);
                }
            }
            #pragma unroll
            for (int ni = 0; ni < 2; ++ni) {
                int brow = wn*32 + ni*16 + lr;
                short8v brh = frag_ld(sBrh, brow, 4*ks + lg);
                short8v bih = frag_ld(sBih, brow, 4*ks + lg);
                short8v brl, bil;
                if constexpr (SPLIT_W) {
                    brl = frag_ld(sBrl, brow, 4*ks + lg);
                    bil = frag_ld(sBil, brow, 4*ks + lg);
                }
                #pragma unroll
                for (int mi = 0; mi < 2; ++mi) {
                    // hi*hi
                    accr[mi][ni] = mfma16(arh[mi],  brh, accr[mi][ni]);
                    accr[mi][ni] = mfma16(aihn[mi], bih, accr[mi][ni]);
                    acci[mi][ni] = mfma16(arh[mi],  bih, acci[mi][ni]);
                    acci[mi][ni] = mfma16(aih[mi],  brh, acci[mi][ni]);
                    if constexpr (SPLIT_W) {   // hi*lo
                        accr[mi][ni] = mfma16(arh[mi],  brl, accr[mi][ni]);
                        accr[mi][ni] = mfma16(aihn[mi], bil, accr[mi][ni]);
                        acci[mi][ni] = mfma16(arh[mi],  bil, acci[mi][ni]);
                        acci[mi][ni] = mfma16(aih[mi],  brl, acci[mi][ni]);
                    }
                    if constexpr (SPLIT_A) {   // lo*hi
                        accr[mi][ni] = mfma16(arl[mi],  brh, accr[mi][ni]);
                        accr[mi][ni] = mfma16(ailn[mi], bih, accr[mi][ni]);
                        acci[mi][ni] = mfma16(arl[mi],  bih, acci[mi][ni]);
                        acci[mi][ni] = mfma16(ail[mi],  brh, acci[mi][ni]);
                    }
                }
            }
        }
        __syncthreads();
    }
}

// ---------------- Kernel 1: complex QKV projection (MFMA, split-precision) ----------------
template<bool FP32>
__device__ void qkv_body(
    const void* xr, const void* xi, const void* fr_, const void* fi_,
    const void* Wr, const void* Wi, const void* bqr, const void* bqi,
    bf16* qr, bf16* qi, bf16* kr, bf16* ki, bf16* vr, bf16* vi,
    bf16 (*sA)[64*64], bf16 (*sB)[64*64])
{
    const int t  = threadIdx.x;
    const int w  = t >> 6, l = t & 63;
    const int lr = l & 15, lg = l >> 4;
    const int wm = w >> 1, wn = w & 1;
    const int row0 = blockIdx.y*64, col0 = blockIdx.x*64;

    f32x4 accr[2][2] = {}, acci[2][2] = {};
    cgemm_core64<FP32, FP32, FP32, FP32>(
        xr, xi, Wr, Wi, row0, col0,
        sA[0], sA[1], sA[2], sA[3], sB[0], sB[1], sB[2], sB[3],
        accr, acci);

    #pragma unroll
    for (int ni = 0; ni < 2; ++ni) {
        int col = col0 + wn*32 + ni*16 + lr;
        float bre = ldin<FP32>(bqr, col);
        float bim = ldin<FP32>(bqi, col);
        int s = col % 3;
        int tc = col / 3;
        int h = tc / HD, d = tc % HD;
        #pragma unroll
        for (int mi = 0; mi < 2; ++mi)
        #pragma unroll
        for (int r = 0; r < 4; ++r) {
            int row = row0 + wm*32 + mi*16 + 4*lg + r;
            int bb = row / N, n = row % N;
            float cr = accr[mi][ni][r] + bre;
            float ci = acci[mi][ni][r] + bim;
            if (s == 2) {
                int idxT = ((bb*HEADS + h)*HD + d)*N + n;   // V transposed [b,h,d,n]
                vr[idxT] = __float2bfloat16(scrub(cr));
                vi[idxT] = __float2bfloat16(scrub(ci));
            } else {
                float fre = ldin<FP32>(fr_, n*HD + d);
                float fim = ldin<FP32>(fi_, n*HD + d);
                float rr = cr*fre - ci*fim;
                float ri = cr*fim + ci*fre;
                int idx = ((bb*HEADS + h)*N + n)*HD + d;
                if (s == 0) { qr[idx] = __float2bfloat16(scrub(rr)); qi[idx] = __float2bfloat16(scrub(ri)); }
                else        { kr[idx] = __float2bfloat16(scrub(rr)); ki[idx] = __float2bfloat16(scrub(ri)); }
            }
        }
    }
}

__global__ __launch_bounds__(256, 2) void qkv_kernel(
    const void* xr, const void* xi, const void* fr_, const void* fi_,
    const void* Wr, const void* Wi, const void* bqr, const void* bqi,
    bf16* qr, bf16* qi, bf16* kr, bf16* ki, bf16* vr, bf16* vi)
{
    __shared__ __align__(16) bf16 sA[4][64*64];   // r_hi, i_hi, r_lo, i_lo
    __shared__ __align__(16) bf16 sB[4][64*64];
    __shared__ int sbad;
    bool f32 = sniff_fp32(xr, threadIdx.x, &sbad);
    if (f32) qkv_body<true >(xr,xi,fr_,fi_,Wr,Wi,bqr,bqi,qr,qi,kr,ki,vr,vi,sA,sB);
    else     qkv_body<false>(xr,xi,fr_,fi_,Wr,Wi,bqr,bqi,qr,qi,kr,ki,vr,vi,sA,sB);
}

// ---------------- Kernel 2: flash-style MFMA attention (R1, unchanged) ----------------
__global__ __launch_bounds__(256) void attn_kernel(
    const bf16* qr, const bf16* qi, const bf16* kr, const bf16* ki,
    const bf16* vtr, const bf16* vti, bf16* aor_, bf16* aoi_)
{
    __shared__ __align__(16) bf16 skr[64*64];
    __shared__ __align__(16) bf16 ski[64*64];
    __shared__ __align__(16) bf16 svr[64*64];   // Vt tile: [d][m]
    __shared__ __align__(16) bf16 svi[64*64];
    __shared__ __align__(16) bf16 sp[4][16*64]; // per-wave P tile

    const int t  = threadIdx.x;
    const int w  = t >> 6;
    const int l  = t & 63;
    const int lr = l & 15;
    const int lg = l >> 4;
    const int qt = blockIdx.x & 15;
    const int bh = blockIdx.x >> 4;

    const size_t hbase = (size_t)bh * N * HD;

    const bf16* qrg = qr + hbase + (size_t)(qt*64 + w*16 + lr) * HD;
    const bf16* qig = qi + hbase + (size_t)(qt*64 + w*16 + lr) * HD;
    short8v qfr[2], qfi[2], qfrn[2];
    #pragma unroll
    for (int ks = 0; ks < 2; ++ks) {
        qfr[ks] = *(const short8v*)(qrg + 32*ks + 8*lg);
        qfi[ks] = *(const short8v*)(qig + 32*ks + 8*lg);
        qfrn[ks] = neg8(qfr[ks]);
    }

    const int cA = t, cB = t + 256;
    const int rA = cA >> 3, jA = (cA & 7) ^ (rA & 7);
    const int rB = cB >> 3, jB = (cB & 7) ^ (rB & 7);
    const bf16* krg = kr  + hbase;
    const bf16* kig = ki  + hbase;
    const bf16* vrg = vtr + hbase;
    const bf16* vig = vti + hbase;

    f32x4 outr[4], outi[4];
    #pragma unroll
    for (int dt = 0; dt < 4; ++dt) {
        outr[dt] = (f32x4){0.f,0.f,0.f,0.f};
        outi[dt] = (f32x4){0.f,0.f,0.f,0.f};
    }
    float mrow[4] = {-1e30f,-1e30f,-1e30f,-1e30f};
    float lrow[4] = {0.f,0.f,0.f,0.f};

    for (int kt = 0; kt < N/64; ++kt) {
        const int m0 = kt*64;
        *(short8v*)(skr + cA*8) = *(const short8v*)(krg + (size_t)(m0+rA)*HD + jA*8);
        *(short8v*)(skr + cB*8) = *(const short8v*)(krg + (size_t)(m0+rB)*HD + jB*8);
        *(short8v*)(ski + cA*8) = *(const short8v*)(kig + (size_t)(m0+rA)*HD + jA*8);
        *(short8v*)(ski + cB*8) = *(const short8v*)(kig + (size_t)(m0+rB)*HD + jB*8);
        *(short8v*)(svr + cA*8) = *(const short8v*)(vrg + (size_t)rA*N + m0 + jA*8);
        *(short8v*)(svr + cB*8) = *(const short8v*)(vrg + (size_t)rB*N + m0 + jB*8);
        *(short8v*)(svi + cA*8) = *(const short8v*)(vig + (size_t)rA*N + m0 + jA*8);
        *(short8v*)(svi + cB*8) = *(const short8v*)(vig + (size_t)rB*N + m0 + jB*8);
        __syncthreads();

        f32x4 sr[4], si[4];
        #pragma unroll
        for (int ct = 0; ct < 4; ++ct) {
            f32x4 ar = (f32x4){0.f,0.f,0.f,0.f};
            f32x4 ai = (f32x4){0.f,0.f,0.f,0.f};
            #pragma unroll
            for (int ks = 0; ks < 2; ++ks) {
                short8v kfr = frag_ld(skr, 16*ct + lr, 4*ks + lg);
                short8v kfi = frag_ld(ski, 16*ct + lr, 4*ks + lg);
                ar = mfma16(qfr[ks],  kfr, ar);
                ar = mfma16(qfi[ks],  kfi, ar);
                ai = mfma16(qfi[ks],  kfr, ai);
                ai = mfma16(qfrn[ks], kfi, ai);
            }
            sr[ct] = ar; si[ct] = ai;
        }

        float p[4][4];
        float pmax[4] = {-1e30f,-1e30f,-1e30f,-1e30f};
        #pragma unroll
        for (int ct = 0; ct < 4; ++ct)
        #pragma unroll
        for (int r = 0; r < 4; ++r) {
            float s = sqrtf(sr[ct][r]*sr[ct][r] + si[ct][r]*si[ct][r]) * 0.125f;
            p[ct][r] = s;
            pmax[r] = fmaxf(pmax[r], s);
        }
        #pragma unroll
        for (int mk = 1; mk <= 8; mk <<= 1)
        #pragma unroll
        for (int r = 0; r < 4; ++r)
            pmax[r] = fmaxf(pmax[r], __shfl_xor(pmax[r], mk));

        float fsc[4];
        #pragma unroll
        for (int r = 0; r < 4; ++r) {
            float mnew = fmaxf(mrow[r], pmax[r]);
            fsc[r] = __expf(mrow[r] - mnew);
            mrow[r] = mnew;
        }
        float rsum[4] = {0.f,0.f,0.f,0.f};
        #pragma unroll
        for (int ct = 0; ct < 4; ++ct)
        #pragma unroll
        for (int r = 0; r < 4; ++r) {
            float e = __expf(p[ct][r] - mrow[r]);
            p[ct][r] = e;
            rsum[r] += e;
        }
        #pragma unroll
        for (int mk = 1; mk <= 8; mk <<= 1)
        #pragma unroll
        for (int r = 0; r < 4; ++r)
            rsum[r] += __shfl_xor(rsum[r], mk);
        #pragma unroll
        for (int r = 0; r < 4; ++r)
            lrow[r] = lrow[r]*fsc[r] + rsum[r];
        #pragma unroll
        for (int dt = 0; dt < 4; ++dt)
        #pragma unroll
        for (int r = 0; r < 4; ++r) {
            outr[dt][r] *= fsc[r];
            outi[dt][r] *= fsc[r];
        }

        bf16* pw = sp[w];
        #pragma unroll
        for (int ct = 0; ct < 4; ++ct)
        #pragma unroll
        for (int r = 0; r < 4; ++r) {
            int prow = 4*lg + r;
            int pcol = 16*ct + lr;
            int jj = (pcol >> 3) ^ (prow & 7);
            pw[prow*64 + jj*8 + (pcol & 7)] = __float2bfloat16(p[ct][r]);
        }
        short8v pa[2];
        #pragma unroll
        for (int ks2 = 0; ks2 < 2; ++ks2)
            pa[ks2] = frag_ld(pw, lr, 4*ks2 + lg);

        #pragma unroll
        for (int dt = 0; dt < 4; ++dt)
        #pragma unroll
        for (int ks2 = 0; ks2 < 2; ++ks2) {
            short8v vfr = frag_ld(svr, 16*dt + lr, 4*ks2 + lg);
            short8v vfi = frag_ld(svi, 16*dt + lr, 4*ks2 + lg);
            outr[dt] = mfma16(pa[ks2], vfr, outr[dt]);
            outi[dt] = mfma16(pa[ks2], vfi, outi[dt]);
        }
        __syncthreads();
    }

    const int b_ = bh / HEADS, h_ = bh % HEADS;
    float invl[4];
    #pragma unroll
    for (int r = 0; r < 4; ++r) invl[r] = 1.0f / lrow[r];
    #pragma unroll
    for (int dt = 0; dt < 4; ++dt)
    #pragma unroll
    for (int r = 0; r < 4; ++r) {
        int n_ = qt*64 + w*16 + 4*lg + r;
        int d_ = 16*dt + lr;
        size_t oidx = ((size_t)(b_*N + n_))*DIM + h_*HD + d_;
        aor_[oidx] = __float2bfloat16(scrub(outr[dt][r]*invl[r]));
        aoi_[oidx] = __float2bfloat16(scrub(outi[dt][r]*invl[r]));
    }
}

// ---------------- Kernel 3: complex out projection (MFMA, split-W) ----------------
template<bool FP32>
__device__ void outproj_body(
    const bf16* ar, const bf16* ai,
    const void* Wr, const void* Wi, const void* bor, const void* boi,
    void* out,
    bf16 (*sA)[64*64], bf16 (*sB)[64*64])
{
    const int t  = threadIdx.x;
    const int w  = t >> 6, l = t & 63;
    const int lr = l & 15, lg = l >> 4;
    const int wm = w >> 1, wn = w & 1;
    const int row0 = blockIdx.y*64, col0 = blockIdx.x*64;

    f32x4 accr[2][2] = {}, acci[2][2] = {};
    // A is attention output: inherently bf16-valued, no split. W: split iff fp32.
    cgemm_core64<false, FP32, false, FP32>(
        ar, ai, Wr, Wi, row0, col0,
        sA[0], sA[1], nullptr, nullptr, sB[0], sB[1], sB[2], sB[3],
        accr, acci);

    #pragma unroll
    for (int ni = 0; ni < 2; ++ni) {
        int col = col0 + wn*32 + ni*16 + lr;
        float bre = ldin<FP32>(bor, col);
        float bim = ldin<FP32>(boi, col);
        #pragma unroll
        for (int mi = 0; mi < 2; ++mi)
        #pragma unroll
        for (int r = 0; r < 4; ++r) {
            int row = row0 + wm*32 + mi*16 + 4*lg + r;
            float cr = scrub(accr[mi][ni][r] + bre);
            float ci = scrub(acci[mi][ni][r] + bim);
            if (FP32) {
                ((float*)out)[(size_t)row*DIM + col]                 = cr;
                ((float*)out)[(size_t)M*DIM + (size_t)row*DIM + col] = ci;
            } else {
                ((bf16*)out)[(size_t)row*DIM + col]                  = __float2bfloat16(cr);
                ((bf16*)out)[(size_t)M*DIM + (size_t)row*DIM + col]  = __float2bfloat16(ci);
            }
        }
    }
}

__global__ __launch_bounds__(256, 2) void outproj_kernel(
    const void* xprobe,
    const bf16* ar, const bf16* ai,
    const void* Wr, const void* Wi, const void* bor, const void* boi,
    void* out)
{
    __shared__ __align__(16) bf16 sA[2][64*64];
    __shared__ __align__(16) bf16 sB[4][64*64];
    __shared__ int sbad;
    bool f32 = sniff_fp32(xprobe, threadIdx.x, &sbad);
    if (f32) outproj_body<true >(ar,ai,Wr,Wi,bor,boi,out,sA,sB);
    else     outproj_body<false>(ar,ai,Wr,Wi,bor,boi,out,sA,sB);
}

extern "C" void kernel_launch(void* const* d_in, const int* in_sizes, int n_in,
                              void* d_out, int out_size, void* d_ws, size_t ws_size,
                              hipStream_t stream)
{
    const void* xr     = d_in[0];
    const void* xi     = d_in[1];
    const void* fr     = d_in[2];
    const void* fi     = d_in[3];
    const void* Wqkv_r = d_in[4];
    const void* Wqkv_i = d_in[5];
    const void* bqkv_r = d_in[6];
    const void* bqkv_i = d_in[7];
    const void* Wout_r = d_in[8];
    const void* Wout_i = d_in[9];
    const void* bout_r = d_in[10];
    const void* bout_i = d_in[11];

    // ws layout: 8 bf16 planes of QS elements = 32 MiB total
    bf16* w = (bf16*)d_ws;
    const size_t QS = (size_t)B*HEADS*N*HD;   // 2,097,152
    bf16* qr   = w;          bf16* qi   = qr  + QS;
    bf16* kr   = qi  + QS;   bf16* ki   = kr  + QS;
    bf16* vr   = ki  + QS;   bf16* vi   = vr  + QS;   // TRANSPOSED [b,h,d,n]
    bf16* aor_ = vi  + QS;   bf16* aoi_ = aor_ + QS;

    qkv_kernel<<<dim3(E3/64, M/64), dim3(256), 0, stream>>>(
        xr, xi, fr, fi, Wqkv_r, Wqkv_i, bqkv_r, bqkv_i, qr, qi, kr, ki, vr, vi);

    attn_kernel<<<dim3(B*HEADS*(N/64)), dim3(256), 0, stream>>>(
        qr, qi, kr, ki, vr, vi, aor_, aoi_);

    outproj_kernel<<<dim3(DIM/64, M/64), dim3(256), 0, stream>>>(
        xr, aor_, aoi_, Wout_r, Wout_i, bout_r, bout_i, d_out);
}

// Round 4
// 385.002 us; speedup vs baseline: 11.5450x; 1.0512x over previous
//
#include <hip/hip_runtime.h>
#include <hip/hip_bf16.h>
#include <stdint.h>

#define B 2
#define N 1024
#define DIM 1024
#define HEADS 16
#define HD 64
#define E3 (3*DIM)
#define M (B*N)

typedef __hip_bfloat16 bf16;
typedef __attribute__((ext_vector_type(8))) short short8v;
typedef __attribute__((ext_vector_type(4))) float f32x4;
typedef __attribute__((ext_vector_type(4))) unsigned int u32x4;

__device__ __forceinline__ float scrub(float v) {
    return (v == v && fabsf(v) < 1e30f) ? v : 0.0f;
}
__device__ __forceinline__ float b2f(bf16 x) { return scrub(__bfloat162float(x)); }

template<bool FP32>
__device__ __forceinline__ float ldin(const void* p, int i) {
    if (FP32) return scrub(((const float*)p)[i]);
    else      return scrub(__bfloat162float(((const bf16*)p)[i]));
}

__device__ __forceinline__ bool sniff_fp32(const void* x, int tid, int* sbad) {
    if (tid == 0) *sbad = 0;
    __syncthreads();
    if (tid < 64) {
        const unsigned short* u = (const unsigned short*)x;
        int ex = (u[tid] >> 7) & 0xFF;
        if (ex == 0xFF || ex >= 135 || (ex != 0 && ex <= 118))
            atomicAdd(sbad, 1);
    }
    __syncthreads();
    return *sbad > 4;
}

__device__ __forceinline__ short f2bs(float x) {
    bf16 h = __float2bfloat16(x);
    return __builtin_bit_cast(short, h);
}
__device__ __forceinline__ short8v neg8(short8v x) {   // flip bf16 sign bits
    u32x4 u = __builtin_bit_cast(u32x4, x);
    u ^= 0x80008000u;
    return __builtin_bit_cast(short8v, u);
}
__device__ __forceinline__ f32x4 mfma16(short8v a, short8v b, f32x4 c) {
    return __builtin_amdgcn_mfma_f32_16x16x32_bf16(a, b, c, 0, 0, 0);
}

// fp32x8 -> (hi, lo) bf16x8 split
__device__ __forceinline__ void cvt8(bf16* dhi, bf16* dlo, const float* s) {
    float4 a = *(const float4*)s;
    float4 b = *(const float4*)(s + 4);
    float v[8] = {a.x,a.y,a.z,a.w,b.x,b.y,b.z,b.w};
    short8v hi, lo;
    #pragma unroll
    for (int e = 0; e < 8; ++e) {
        float f = scrub(v[e]);
        bf16 h = __float2bfloat16(f);
        hi[e] = __builtin_bit_cast(short, h);
        lo[e] = f2bs(f - __bfloat162float(h));
    }
    *(short8v*)dhi = hi;
    *(short8v*)dlo = lo;
}

// ================= LDS layout, BK=32 =================
// Rows of 32 bf16 (64 B = 4 chunks of 16 B). Chunk j of row r lives at
// physical chunk (j ^ (r&3)) — involution applied at staging-source and reads.
// A wave's 4 lane-groups cover all 4 chunks of each row -> balanced banks.
#define PL (64*32)   // one plane: 64 rows x 32 bf16

__device__ __forceinline__ short8v frag_ld32(const bf16* base, int row, int j) {
    return *(const short8v*)(base + row*32 + ((j ^ (row & 3)) << 3));
}

// ================= complex bf16 MFMA GEMM core =================
// C[row,col] = sum_k A[row,k]*W[col,k] (complex). Tile 64x64, BK=32.
// 4 waves 2x2; wave owns 32x32 = 2x2 fragments.
// MODE: 0 = bf16 direct (4 MFMA/step), 1 = pre-split planes (copies),
//       2 = fp32 inline convert. 1&2: operand = hi+lo (lo*lo dropped).
// accr collects Ar*Br-type terms, accs collects Ai*Bi (subtract at epi), acci = imag.
template<int AMODE, int BMODE>
__device__ __forceinline__ void cgemm32(
    const void* Aor, const void* Aoi,
    const bf16* Arh, const bf16* Aih, const bf16* Arl, const bf16* Ail,
    const void* Bor, const void* Boi,
    const bf16* Brh, const bf16* Bih, const bf16* Brl, const bf16* Bil,
    int row0, int col0,
    bf16* sA, bf16* sB,
    f32x4 (*accr)[2], f32x4 (*accs)[2], f32x4 (*acci)[2])
{
    const int t  = threadIdx.x;
    const int w  = t >> 6, l = t & 63;
    const int lr = l & 15, lg = l >> 4;
    const int wm = w >> 1, wn = w & 1;

    const int srow = t >> 2;
    const int sj   = (t & 3) ^ (srow & 3);

    for (int k0 = 0; k0 < DIM; k0 += 32) {
        const size_t aoff = (size_t)(row0 + srow)*DIM + k0 + sj*8;
        const size_t boff = (size_t)(col0 + srow)*DIM + k0 + sj*8;
        bf16* dA = sA + t*8;
        bf16* dB = sB + t*8;
        if constexpr (AMODE == 0) {
            *(short8v*)(dA)        = *(const short8v*)((const bf16*)Aor + aoff);
            *(short8v*)(dA + PL)   = *(const short8v*)((const bf16*)Aoi + aoff);
        } else if constexpr (AMODE == 1) {
            *(short8v*)(dA)        = *(const short8v*)(Arh + aoff);
            *(short8v*)(dA + PL)   = *(const short8v*)(Aih + aoff);
            *(short8v*)(dA + 2*PL) = *(const short8v*)(Arl + aoff);
            *(short8v*)(dA + 3*PL) = *(const short8v*)(Ail + aoff);
        } else {
            cvt8(dA,      dA + 2*PL, (const float*)Aor + aoff);
            cvt8(dA + PL, dA + 3*PL, (const float*)Aoi + aoff);
        }
        if constexpr (BMODE == 0) {
            *(short8v*)(dB)        = *(const short8v*)((const bf16*)Bor + boff);
            *(short8v*)(dB + PL)   = *(const short8v*)((const bf16*)Boi + boff);
        } else if constexpr (BMODE == 1) {
            *(short8v*)(dB)        = *(const short8v*)(Brh + boff);
            *(short8v*)(dB + PL)   = *(const short8v*)(Bih + boff);
            *(short8v*)(dB + 2*PL) = *(const short8v*)(Brl + boff);
            *(short8v*)(dB + 3*PL) = *(const short8v*)(Bil + boff);
        } else {
            cvt8(dB,      dB + 2*PL, (const float*)Bor + boff);
            cvt8(dB + PL, dB + 3*PL, (const float*)Boi + boff);
        }
        __syncthreads();

        short8v arh[2], aih[2], arl[2], ail[2];
        #pragma unroll
        for (int mi = 0; mi < 2; ++mi) {
            int arow = wm*32 + mi*16 + lr;
            arh[mi] = frag_ld32(sA,      arow, lg);
            aih[mi] = frag_ld32(sA + PL, arow, lg);
            if constexpr (AMODE != 0) {
                arl[mi] = frag_ld32(sA + 2*PL, arow, lg);
                ail[mi] = frag_ld32(sA + 3*PL, arow, lg);
            }
        }
        #pragma unroll
        for (int ni = 0; ni < 2; ++ni) {
            int brow = wn*32 + ni*16 + lr;
            short8v brh = frag_ld32(sB,      brow, lg);
            short8v bih = frag_ld32(sB + PL, brow, lg);
            short8v brl, bil;
            if constexpr (BMODE != 0) {
                brl = frag_ld32(sB + 2*PL, brow, lg);
                bil = frag_ld32(sB + 3*PL, brow, lg);
            }
            #pragma unroll
            for (int mi = 0; mi < 2; ++mi) {
                accr[mi][ni] = mfma16(arh[mi], brh, accr[mi][ni]);
                accs[mi][ni] = mfma16(aih[mi], bih, accs[mi][ni]);
                acci[mi][ni] = mfma16(arh[mi], bih, acci[mi][ni]);
                acci[mi][ni] = mfma16(aih[mi], brh, acci[mi][ni]);
                if constexpr (BMODE != 0) {   // hi * lo
                    accr[mi][ni] = mfma16(arh[mi], brl, accr[mi][ni]);
                    accs[mi][ni] = mfma16(aih[mi], bil, accs[mi][ni]);
                    acci[mi][ni] = mfma16(arh[mi], bil, acci[mi][ni]);
                    acci[mi][ni] = mfma16(aih[mi], brl, acci[mi][ni]);
                }
                if constexpr (AMODE != 0) {   // lo * hi
                    accr[mi][ni] = mfma16(arl[mi], brh, accr[mi][ni]);
                    accs[mi][ni] = mfma16(ail[mi], bih, accs[mi][ni]);
                    acci[mi][ni] = mfma16(arl[mi], bih, acci[mi][ni]);
                    acci[mi][ni] = mfma16(ail[mi], brh, acci[mi][ni]);
                }
            }
        }
        __syncthreads();
    }
}

// ================= prepass: fp32 -> hi/lo bf16 split planes =================
struct PrepArgs {
    const void* src[6];
    bf16* hi[6];
    bf16* lo[6];
    int n8[6];
};

__global__ __launch_bounds__(256) void prepass_kernel(PrepArgs a) {
    __shared__ int sbad;
    const int y = blockIdx.y;
    bool f32 = sniff_fp32(a.src[y], threadIdx.x, &sbad);
    if (!f32) return;   // bf16 inputs: planes unused downstream
    const int n8 = a.n8[y];
    for (int i = blockIdx.x*blockDim.x + threadIdx.x; i < n8; i += gridDim.x*blockDim.x)
        cvt8(a.hi[y] + (size_t)i*8, a.lo[y] + (size_t)i*8, (const float*)a.src[y] + (size_t)i*8);
}

// ================= Kernel 1: complex QKV projection =================
template<bool FP32>
__device__ __forceinline__ void qkv_epi(
    const void* fr_, const void* fi_, const void* bqr, const void* bqi,
    bf16* qr, bf16* qi, bf16* kr, bf16* ki, bf16* vr, bf16* vi,
    int row0, int col0,
    f32x4 (*accr)[2], f32x4 (*accs)[2], f32x4 (*acci)[2])
{
    const int t  = threadIdx.x;
    const int w  = t >> 6, l = t & 63;
    const int lr = l & 15, lg = l >> 4;
    const int wm = w >> 1, wn = w & 1;

    #pragma unroll
    for (int ni = 0; ni < 2; ++ni) {
        int col = col0 + wn*32 + ni*16 + lr;
        float bre = ldin<FP32>(bqr, col);
        float bim = ldin<FP32>(bqi, col);
        int s = col % 3;
        int tc = col / 3;
        int h = tc / HD, d = tc % HD;
        #pragma unroll
        for (int mi = 0; mi < 2; ++mi)
        #pragma unroll
        for (int r = 0; r < 4; ++r) {
            int row = row0 + wm*32 + mi*16 + 4*lg + r;
            int bb = row / N, n = row % N;
            float cr = accr[mi][ni][r] - accs[mi][ni][r] + bre;
            float ci = acci[mi][ni][r] + bim;
            if (s == 2) {
                int idxT = ((bb*HEADS + h)*HD + d)*N + n;   // V transposed [b,h,d,n]
                vr[idxT] = __float2bfloat16(scrub(cr));
                vi[idxT] = __float2bfloat16(scrub(ci));
            } else {
                float fre = ldin<FP32>(fr_, n*HD + d);
                float fim = ldin<FP32>(fi_, n*HD + d);
                float rr = cr*fre - ci*fim;
                float ri = cr*fim + ci*fre;
                int idx = ((bb*HEADS + h)*N + n)*HD + d;
                if (s == 0) { qr[idx] = __float2bfloat16(scrub(rr)); qi[idx] = __float2bfloat16(scrub(ri)); }
                else        { kr[idx] = __float2bfloat16(scrub(rr)); ki[idx] = __float2bfloat16(scrub(ri)); }
            }
        }
    }
}

template<int FM>   // 1 = pre-split planes, 2 = inline convert (ws fallback)
__global__ __launch_bounds__(256, 4) void qkv_kernel(
    const void* xr, const void* xi, const void* fr_, const void* fi_,
    const void* Wr, const void* Wi, const void* bqr, const void* bqi,
    const bf16* xrh, const bf16* xih, const bf16* xrl, const bf16* xil,
    const bf16* wrh, const bf16* wih, const bf16* wrl, const bf16* wil,
    bf16* qr, bf16* qi, bf16* kr, bf16* ki, bf16* vr, bf16* vi)
{
    __shared__ __align__(16) bf16 sA[4*PL], sB[4*PL];
    __shared__ int sbad;
    bool f32 = sniff_fp32(xr, threadIdx.x, &sbad);

    // XCD-chunked swizzle (grid = 1536, %8 == 0)
    const int CB = E3/64;
    int wg = blockIdx.x;
    int sw = (wg & 7) * ((int)gridDim.x >> 3) + (wg >> 3);
    int row0 = (sw / CB) * 64, col0 = (sw % CB) * 64;

    f32x4 accr[2][2] = {}, accs[2][2] = {}, acci[2][2] = {};
    if (f32) {
        cgemm32<FM, FM>(xr, xi, xrh, xih, xrl, xil,
                        Wr, Wi, wrh, wih, wrl, wil,
                        row0, col0, sA, sB, accr, accs, acci);
        qkv_epi<true >(fr_, fi_, bqr, bqi, qr,qi,kr,ki,vr,vi, row0, col0, accr, accs, acci);
    } else {
        cgemm32<0, 0>(xr, xi, nullptr, nullptr, nullptr, nullptr,
                      Wr, Wi, nullptr, nullptr, nullptr, nullptr,
                      row0, col0, sA, sB, accr, accs, acci);
        qkv_epi<false>(fr_, fi_, bqr, bqi, qr,qi,kr,ki,vr,vi, row0, col0, accr, accs, acci);
    }
}

// ================= Kernel 2: flash-style MFMA attention =================
__device__ __forceinline__ short8v frag_ld(const bf16* base, int row, int j) {
    return *(const short8v*)(base + row*64 + ((j ^ (row & 7)) << 3));
}

__global__ __launch_bounds__(256) void attn_kernel(
    const bf16* qr, const bf16* qi, const bf16* kr, const bf16* ki,
    const bf16* vtr, const bf16* vti, bf16* aor_, bf16* aoi_)
{
    __shared__ __align__(16) bf16 skr[64*64];
    __shared__ __align__(16) bf16 ski[64*64];
    __shared__ __align__(16) bf16 svr[64*64];   // Vt tile: [d][m]
    __shared__ __align__(16) bf16 svi[64*64];
    __shared__ __align__(16) bf16 sp[4][16*64]; // per-wave P tile

    const int t  = threadIdx.x;
    const int w  = t >> 6;
    const int l  = t & 63;
    const int lr = l & 15;
    const int lg = l >> 4;
    // XCD-chunked swizzle (grid = 512, %8 == 0): blocks of one (b,h) stay on one XCD
    int wg = blockIdx.x;
    int sw = (wg & 7) * ((int)gridDim.x >> 3) + (wg >> 3);
    const int qt = sw & 15;
    const int bh = sw >> 4;

    const size_t hbase = (size_t)bh * N * HD;

    const bf16* qrg = qr + hbase + (size_t)(qt*64 + w*16 + lr) * HD;
    const bf16* qig = qi + hbase + (size_t)(qt*64 + w*16 + lr) * HD;
    short8v qfr[2], qfi[2], qfrn[2];
    #pragma unroll
    for (int ks = 0; ks < 2; ++ks) {
        qfr[ks] = *(const short8v*)(qrg + 32*ks + 8*lg);
        qfi[ks] = *(const short8v*)(qig + 32*ks + 8*lg);
        qfrn[ks] = neg8(qfr[ks]);
    }

    const int cA = t, cB = t + 256;
    const int rA = cA >> 3, jA = (cA & 7) ^ (rA & 7);
    const int rB = cB >> 3, jB = (cB & 7) ^ (rB & 7);
    const bf16* krg = kr  + hbase;
    const bf16* kig = ki  + hbase;
    const bf16* vrg = vtr + hbase;
    const bf16* vig = vti + hbase;

    f32x4 outr[4], outi[4];
    #pragma unroll
    for (int dt = 0; dt < 4; ++dt) {
        outr[dt] = (f32x4){0.f,0.f,0.f,0.f};
        outi[dt] = (f32x4){0.f,0.f,0.f,0.f};
    }
    float mrow[4] = {-1e30f,-1e30f,-1e30f,-1e30f};
    float lrow[4] = {0.f,0.f,0.f,0.f};

    for (int kt = 0; kt < N/64; ++kt) {
        const int m0 = kt*64;
        *(short8v*)(skr + cA*8) = *(const short8v*)(krg + (size_t)(m0+rA)*HD + jA*8);
        *(short8v*)(skr + cB*8) = *(const short8v*)(krg + (size_t)(m0+rB)*HD + jB*8);
        *(short8v*)(ski + cA*8) = *(const short8v*)(kig + (size_t)(m0+rA)*HD + jA*8);
        *(short8v*)(ski + cB*8) = *(const short8v*)(kig + (size_t)(m0+rB)*HD + jB*8);
        *(short8v*)(svr + cA*8) = *(const short8v*)(vrg + (size_t)rA*N + m0 + jA*8);
        *(short8v*)(svr + cB*8) = *(const short8v*)(vrg + (size_t)rB*N + m0 + jB*8);
        *(short8v*)(svi + cA*8) = *(const short8v*)(vig + (size_t)rA*N + m0 + jA*8);
        *(short8v*)(svi + cB*8) = *(const short8v*)(vig + (size_t)rB*N + m0 + jB*8);
        __syncthreads();

        f32x4 sr[4], si[4];
        #pragma unroll
        for (int ct = 0; ct < 4; ++ct) {
            f32x4 ar = (f32x4){0.f,0.f,0.f,0.f};
            f32x4 ai = (f32x4){0.f,0.f,0.f,0.f};
            #pragma unroll
            for (int ks = 0; ks < 2; ++ks) {
                short8v kfr = frag_ld(skr, 16*ct + lr, 4*ks + lg);
                short8v kfi = frag_ld(ski, 16*ct + lr, 4*ks + lg);
                ar = mfma16(qfr[ks],  kfr, ar);
                ar = mfma16(qfi[ks],  kfi, ar);
                ai = mfma16(qfi[ks],  kfr, ai);
                ai = mfma16(qfrn[ks], kfi, ai);
            }
            sr[ct] = ar; si[ct] = ai;
        }

        float p[4][4];
        float pmax[4] = {-1e30f,-1e30f,-1e30f,-1e30f};
        #pragma unroll
        for (int ct = 0; ct < 4; ++ct)
        #pragma unroll
        for (int r = 0; r < 4; ++r) {
            float s = sqrtf(sr[ct][r]*sr[ct][r] + si[ct][r]*si[ct][r]) * 0.125f;
            p[ct][r] = s;
            pmax[r] = fmaxf(pmax[r], s);
        }
        #pragma unroll
        for (int mk = 1; mk <= 8; mk <<= 1)
        #pragma unroll
        for (int r = 0; r < 4; ++r)
            pmax[r] = fmaxf(pmax[r], __shfl_xor(pmax[r], mk));

        float fsc[4];
        #pragma unroll
        for (int r = 0; r < 4; ++r) {
            float mnew = fmaxf(mrow[r], pmax[r]);
            fsc[r] = __expf(mrow[r] - mnew);
            mrow[r] = mnew;
        }
        float rsum[4] = {0.f,0.f,0.f,0.f};
        #pragma unroll
        for (int ct = 0; ct < 4; ++ct)
        #pragma unroll
        for (int r = 0; r < 4; ++r) {
            float e = __expf(p[ct][r] - mrow[r]);
            p[ct][r] = e;
            rsum[r] += e;
        }
        #pragma unroll
        for (int mk = 1; mk <= 8; mk <<= 1)
        #pragma unroll
        for (int r = 0; r < 4; ++r)
            rsum[r] += __shfl_xor(rsum[r], mk);
        #pragma unroll
        for (int r = 0; r < 4; ++r)
            lrow[r] = lrow[r]*fsc[r] + rsum[r];
        #pragma unroll
        for (int dt = 0; dt < 4; ++dt)
        #pragma unroll
        for (int r = 0; r < 4; ++r) {
            outr[dt][r] *= fsc[r];
            outi[dt][r] *= fsc[r];
        }

        bf16* pw = sp[w];
        #pragma unroll
        for (int ct = 0; ct < 4; ++ct)
        #pragma unroll
        for (int r = 0; r < 4; ++r) {
            int prow = 4*lg + r;
            int pcol = 16*ct + lr;
            int jj = (pcol >> 3) ^ (prow & 7);
            pw[prow*64 + jj*8 + (pcol & 7)] = __float2bfloat16(p[ct][r]);
        }
        short8v pa[2];
        #pragma unroll
        for (int ks2 = 0; ks2 < 2; ++ks2)
            pa[ks2] = frag_ld(pw, lr, 4*ks2 + lg);

        #pragma unroll
        for (int dt = 0; dt < 4; ++dt)
        #pragma unroll
        for (int ks2 = 0; ks2 < 2; ++ks2) {
            short8v vfr = frag_ld(svr, 16*dt + lr, 4*ks2 + lg);
            short8v vfi = frag_ld(svi, 16*dt + lr, 4*ks2 + lg);
            outr[dt] = mfma16(pa[ks2], vfr, outr[dt]);
            outi[dt] = mfma16(pa[ks2], vfi, outi[dt]);
        }
        __syncthreads();
    }

    const int b_ = bh / HEADS, h_ = bh % HEADS;
    float invl[4];
    #pragma unroll
    for (int r = 0; r < 4; ++r) invl[r] = 1.0f / lrow[r];
    #pragma unroll
    for (int dt = 0; dt < 4; ++dt)
    #pragma unroll
    for (int r = 0; r < 4; ++r) {
        int n_ = qt*64 + w*16 + 4*lg + r;
        int d_ = 16*dt + lr;
        size_t oidx = ((size_t)(b_*N + n_))*DIM + h_*HD + d_;
        aor_[oidx] = __float2bfloat16(scrub(outr[dt][r]*invl[r]));
        aoi_[oidx] = __float2bfloat16(scrub(outi[dt][r]*invl[r]));
    }
}

// ================= Kernel 3: complex out projection =================
template<int FM>
__global__ __launch_bounds__(256, 4) void outproj_kernel(
    const void* xprobe,
    const bf16* ar, const bf16* ai,
    const void* Wr, const void* Wi, const void* bor, const void* boi,
    const bf16* wrh, const bf16* wih, const bf16* wrl, const bf16* wil,
    void* out)
{
    __shared__ __align__(16) bf16 sA[2*PL], sB[4*PL];
    __shared__ int sbad;
    bool f32 = sniff_fp32(xprobe, threadIdx.x, &sbad);

    const int CB = DIM/64;
    int wg = blockIdx.x;
    int sw = (wg & 7) * ((int)gridDim.x >> 3) + (wg >> 3);
    int row0 = (sw / CB) * 64, col0 = (sw % CB) * 64;

    const int t  = threadIdx.x;
    const int w  = t >> 6, l = t & 63;
    const int lr = l & 15, lg = l >> 4;
    const int wm = w >> 1, wn = w & 1;

    f32x4 accr[2][2] = {}, accs[2][2] = {}, acci[2][2] = {};
    if (f32)
        cgemm32<0, FM>(ar, ai, nullptr, nullptr, nullptr, nullptr,
                       Wr, Wi, wrh, wih, wrl, wil,
                       row0, col0, sA, sB, accr, accs, acci);
    else
        cgemm32<0, 0>(ar, ai, nullptr, nullptr, nullptr, nullptr,
                      Wr, Wi, nullptr, nullptr, nullptr, nullptr,
                      row0, col0, sA, sB, accr, accs, acci);

    #pragma unroll
    for (int ni = 0; ni < 2; ++ni) {
        int col = col0 + wn*32 + ni*16 + lr;
        float bre = f32 ? ldin<true>(bor, col) : ldin<false>(bor, col);
        float bim = f32 ? ldin<true>(boi, col) : ldin<false>(boi, col);
        #pragma unroll
        for (int mi = 0; mi < 2; ++mi)
        #pragma unroll
        for (int r = 0; r < 4; ++r) {
            int row = row0 + wm*32 + mi*16 + 4*lg + r;
            float cr = scrub(accr[mi][ni][r] - accs[mi][ni][r] + bre);
            float ci = scrub(acci[mi][ni][r] + bim);
            if (f32) {
                ((float*)out)[(size_t)row*DIM + col]                 = cr;
                ((float*)out)[(size_t)M*DIM + (size_t)row*DIM + col] = ci;
            } else {
                ((bf16*)out)[(size_t)row*DIM + col]                  = __float2bfloat16(cr);
                ((bf16*)out)[(size_t)M*DIM + (size_t)row*DIM + col]  = __float2bfloat16(ci);
            }
        }
    }
}

// ================= host =================
extern "C" void kernel_launch(void* const* d_in, const int* in_sizes, int n_in,
                              void* d_out, int out_size, void* d_ws, size_t ws_size,
                              hipStream_t stream)
{
    const void* xr     = d_in[0];
    const void* xi     = d_in[1];
    const void* fr     = d_in[2];
    const void* fi     = d_in[3];
    const void* Wqkv_r = d_in[4];
    const void* Wqkv_i = d_in[5];
    const void* bqkv_r = d_in[6];
    const void* bqkv_i = d_in[7];
    const void* Wout_r = d_in[8];
    const void* Wout_i = d_in[9];
    const void* bout_r = d_in[10];
    const void* bout_i = d_in[11];

    bf16* w = (bf16*)d_ws;
    const size_t QS  = (size_t)B*HEADS*N*HD;   // 2,097,152
    const size_t XS  = (size_t)M*DIM;          // 2,097,152
    const size_t WQS = (size_t)E3*DIM;         // 3,145,728
    const size_t WOS = (size_t)DIM*DIM;        // 1,048,576

    bf16* qr   = w;          bf16* qi   = qr  + QS;
    bf16* kr   = qi  + QS;   bf16* ki   = kr  + QS;
    bf16* vr   = ki  + QS;   bf16* vi   = vr  + QS;   // TRANSPOSED [b,h,d,n]
    bf16* aor_ = vi  + QS;   bf16* aoi_ = aor_ + QS;
    bf16* xrh = aoi_ + QS;   bf16* xih = xrh + XS;
    bf16* xrl = xih + XS;    bf16* xil = xrl + XS;
    bf16* wqrh = xil + XS;   bf16* wqih = wqrh + WQS;
    bf16* wqrl = wqih + WQS; bf16* wqil = wqrl + WQS;
    bf16* worh = wqil + WQS; bf16* woih = worh + WOS;
    bf16* worl = woih + WOS; bf16* woil = worl + WOS;

    const size_t need = (size_t)(8*QS + 4*XS + 4*WQS + 4*WOS) * sizeof(bf16);
    const bool pre = ws_size >= need;

    if (pre) {
        PrepArgs a;
        a.src[0] = xr;     a.hi[0] = xrh;  a.lo[0] = xrl;  a.n8[0] = (int)(XS/8);
        a.src[1] = xi;     a.hi[1] = xih;  a.lo[1] = xil;  a.n8[1] = (int)(XS/8);
        a.src[2] = Wqkv_r; a.hi[2] = wqrh; a.lo[2] = wqrl; a.n8[2] = (int)(WQS/8);
        a.src[3] = Wqkv_i; a.hi[3] = wqih; a.lo[3] = wqil; a.n8[3] = (int)(WQS/8);
        a.src[4] = Wout_r; a.hi[4] = worh; a.lo[4] = worl; a.n8[4] = (int)(WOS/8);
        a.src[5] = Wout_i; a.hi[5] = woih; a.lo[5] = woil; a.n8[5] = (int)(WOS/8);
        prepass_kernel<<<dim3(1536, 6), dim3(256), 0, stream>>>(a);

        qkv_kernel<1><<<dim3((E3/64)*(M/64)), dim3(256), 0, stream>>>(
            xr, xi, fr, fi, Wqkv_r, Wqkv_i, bqkv_r, bqkv_i,
            xrh, xih, xrl, xil, wqrh, wqih, wqrl, wqil,
            qr, qi, kr, ki, vr, vi);
    } else {
        qkv_kernel<2><<<dim3((E3/64)*(M/64)), dim3(256), 0, stream>>>(
            xr, xi, fr, fi, Wqkv_r, Wqkv_i, bqkv_r, bqkv_i,
            nullptr, nullptr, nullptr, nullptr, nullptr, nullptr, nullptr, nullptr,
            qr, qi, kr, ki, vr, vi);
    }

    attn_kernel<<<dim3(B*HEADS*(N/64)), dim3(256), 0, stream>>>(
        qr, qi, kr, ki, vr, vi, aor_, aoi_);

    if (pre) {
        outproj_kernel<1><<<dim3((DIM/64)*(M/64)), dim3(256), 0, stream>>>(
            xr, aor_, aoi_, Wout_r, Wout_i, bout_r, bout_i,
            worh, woih, worl, woil, d_out);
    } else {
        outproj_kernel<2><<<dim3((DIM/64)*(M/64)), dim3(256), 0, stream>>>(
            xr, aor_, aoi_, Wout_r, Wout_i, bout_r, bout_i,
            nullptr, nullptr, nullptr, nullptr, d_out);
    }
}

// Round 7
// 366.131 us; speedup vs baseline: 12.1400x; 1.0515x over previous
//
#include <hip/hip_runtime.h>
#include <hip/hip_bf16.h>
#include <stdint.h>

#define B 2
#define N 1024
#define DIM 1024
#define HEADS 16
#define HD 64
#define E3 (3*DIM)
#define M (B*N)

typedef __hip_bfloat16 bf16;
typedef __attribute__((ext_vector_type(8))) short short8v;
typedef __attribute__((ext_vector_type(4))) float f32x4;
typedef __attribute__((ext_vector_type(4))) unsigned int u32x4;

__device__ __forceinline__ float scrub(float v) {
    return (v == v && fabsf(v) < 1e30f) ? v : 0.0f;
}
__device__ __forceinline__ float b2f(bf16 x) { return scrub(__bfloat162float(x)); }

template<bool FP32>
__device__ __forceinline__ float ldin(const void* p, int i) {
    if (FP32) return scrub(((const float*)p)[i]);
    else      return scrub(__bfloat162float(((const bf16*)p)[i]));
}

__device__ __forceinline__ bool sniff_fp32(const void* x, int tid, int* sbad) {
    if (tid == 0) *sbad = 0;
    __syncthreads();
    if (tid < 64) {
        const unsigned short* u = (const unsigned short*)x;
        int ex = (u[tid] >> 7) & 0xFF;
        if (ex == 0xFF || ex >= 135 || (ex != 0 && ex <= 118))
            atomicAdd(sbad, 1);
    }
    __syncthreads();
    return *sbad > 4;
}

__device__ __forceinline__ short f2bs(float x) {
    bf16 h = __float2bfloat16(x);
    return __builtin_bit_cast(short, h);
}
__device__ __forceinline__ short8v neg8(short8v x) {   // flip bf16 sign bits
    u32x4 u = __builtin_bit_cast(u32x4, x);
    u ^= 0x80008000u;
    return __builtin_bit_cast(short8v, u);
}
__device__ __forceinline__ f32x4 mfma16(short8v a, short8v b, f32x4 c) {
    return __builtin_amdgcn_mfma_f32_16x16x32_bf16(a, b, c, 0, 0, 0);
}

// fp32x8 -> (hi, lo) bf16x8 split
__device__ __forceinline__ void cvt8(bf16* dhi, bf16* dlo, const float* s) {
    float4 a = *(const float4*)s;
    float4 b = *(const float4*)(s + 4);
    float v[8] = {a.x,a.y,a.z,a.w,b.x,b.y,b.z,b.w};
    short8v hi, lo;
    #pragma unroll
    for (int e = 0; e < 8; ++e) {
        float f = scrub(v[e]);
        bf16 h = __float2bfloat16(f);
        hi[e] = __builtin_bit_cast(short, h);
        lo[e] = f2bs(f - __bfloat162float(h));
    }
    *(short8v*)dhi = hi;
    *(short8v*)dlo = lo;
}

// ================= LDS layout, BK=32 — R4-proven =================
#define PL (64*32)   // one plane: 64 rows x 32 bf16

__device__ __forceinline__ short8v frag_ld32(const bf16* base, int row, int j) {
    return *(const short8v*)(base + row*32 + ((j ^ (row & 3)) << 3));
}

// ================= complex bf16 MFMA GEMM core (R4-proven) =================
// C[row,col] = sum_k A[row,k]*W[col,k] (complex). Tile 64x64, BK=32.
// MODE: 0 = bf16 direct; 1 = pre-split hi/lo planes; 2 = fp32 inline convert;
//       3 = single bf16-hi plane (no lo terms).
// accr = Ar*Br terms, accs = Ai*Bi (subtract at epi), acci = imag.
template<int AMODE, int BMODE>
__device__ __forceinline__ void cgemm32(
    const void* Aor, const void* Aoi,
    const bf16* Arh, const bf16* Aih, const bf16* Arl, const bf16* Ail,
    const void* Bor, const void* Boi,
    const bf16* Brh, const bf16* Bih, const bf16* Brl, const bf16* Bil,
    int row0, int col0,
    bf16* sA, bf16* sB,
    f32x4 (*accr)[2], f32x4 (*accs)[2], f32x4 (*acci)[2])
{
    constexpr bool ALO = (AMODE == 1 || AMODE == 2);
    constexpr bool BLO = (BMODE == 1 || BMODE == 2);

    const int t  = threadIdx.x;
    const int w  = t >> 6, l = t & 63;
    const int lr = l & 15, lg = l >> 4;
    const int wm = w >> 1, wn = w & 1;

    const int srow = t >> 2;
    const int sj   = (t & 3) ^ (srow & 3);

    for (int k0 = 0; k0 < DIM; k0 += 32) {
        const size_t aoff = (size_t)(row0 + srow)*DIM + k0 + sj*8;
        const size_t boff = (size_t)(col0 + srow)*DIM + k0 + sj*8;
        bf16* dA = sA + t*8;
        bf16* dB = sB + t*8;
        if constexpr (AMODE == 0) {
            *(short8v*)(dA)        = *(const short8v*)((const bf16*)Aor + aoff);
            *(short8v*)(dA + PL)   = *(const short8v*)((const bf16*)Aoi + aoff);
        } else if constexpr (AMODE == 1) {
            *(short8v*)(dA)        = *(const short8v*)(Arh + aoff);
            *(short8v*)(dA + PL)   = *(const short8v*)(Aih + aoff);
            *(short8v*)(dA + 2*PL) = *(const short8v*)(Arl + aoff);
            *(short8v*)(dA + 3*PL) = *(const short8v*)(Ail + aoff);
        } else if constexpr (AMODE == 3) {
            *(short8v*)(dA)        = *(const short8v*)(Arh + aoff);
            *(short8v*)(dA + PL)   = *(const short8v*)(Aih + aoff);
        } else {
            cvt8(dA,      dA + 2*PL, (const float*)Aor + aoff);
            cvt8(dA + PL, dA + 3*PL, (const float*)Aoi + aoff);
        }
        if constexpr (BMODE == 0) {
            *(short8v*)(dB)        = *(const short8v*)((const bf16*)Bor + boff);
            *(short8v*)(dB + PL)   = *(const short8v*)((const bf16*)Boi + boff);
        } else if constexpr (BMODE == 1) {
            *(short8v*)(dB)        = *(const short8v*)(Brh + boff);
            *(short8v*)(dB + PL)   = *(const short8v*)(Bih + boff);
            *(short8v*)(dB + 2*PL) = *(const short8v*)(Brl + boff);
            *(short8v*)(dB + 3*PL) = *(const short8v*)(Bil + boff);
        } else if constexpr (BMODE == 3) {
            *(short8v*)(dB)        = *(const short8v*)(Brh + boff);
            *(short8v*)(dB + PL)   = *(const short8v*)(Bih + boff);
        } else {
            cvt8(dB,      dB + 2*PL, (const float*)Bor + boff);
            cvt8(dB + PL, dB + 3*PL, (const float*)Boi + boff);
        }
        __syncthreads();

        short8v arh[2], aih[2], arl[2], ail[2];
        #pragma unroll
        for (int mi = 0; mi < 2; ++mi) {
            int arow = wm*32 + mi*16 + lr;
            arh[mi] = frag_ld32(sA,      arow, lg);
            aih[mi] = frag_ld32(sA + PL, arow, lg);
            if constexpr (ALO) {
                arl[mi] = frag_ld32(sA + 2*PL, arow, lg);
                ail[mi] = frag_ld32(sA + 3*PL, arow, lg);
            }
        }
        #pragma unroll
        for (int ni = 0; ni < 2; ++ni) {
            int brow = wn*32 + ni*16 + lr;
            short8v brh = frag_ld32(sB,      brow, lg);
            short8v bih = frag_ld32(sB + PL, brow, lg);
            short8v brl, bil;
            if constexpr (BLO) {
                brl = frag_ld32(sB + 2*PL, brow, lg);
                bil = frag_ld32(sB + 3*PL, brow, lg);
            }
            #pragma unroll
            for (int mi = 0; mi < 2; ++mi) {
                accr[mi][ni] = mfma16(arh[mi], brh, accr[mi][ni]);
                accs[mi][ni] = mfma16(aih[mi], bih, accs[mi][ni]);
                acci[mi][ni] = mfma16(arh[mi], bih, acci[mi][ni]);
                acci[mi][ni] = mfma16(aih[mi], brh, acci[mi][ni]);
                if constexpr (BLO) {   // hi * lo
                    accr[mi][ni] = mfma16(arh[mi], brl, accr[mi][ni]);
                    accs[mi][ni] = mfma16(aih[mi], bil, accs[mi][ni]);
                    acci[mi][ni] = mfma16(arh[mi], bil, acci[mi][ni]);
                    acci[mi][ni] = mfma16(aih[mi], brl, acci[mi][ni]);
                }
                if constexpr (ALO) {   // lo * hi
                    accr[mi][ni] = mfma16(arl[mi], brh, accr[mi][ni]);
                    accs[mi][ni] = mfma16(ail[mi], bih, accs[mi][ni]);
                    acci[mi][ni] = mfma16(arl[mi], bih, acci[mi][ni]);
                    acci[mi][ni] = mfma16(ail[mi], brh, acci[mi][ni]);
                }
            }
        }
        __syncthreads();
    }
}

// ================= prepass: fp32 -> hi/lo bf16 split planes =================
struct PrepArgs {
    const void* src[6];
    bf16* hi[6];
    bf16* lo[6];
    int n8[6];
};

__global__ __launch_bounds__(256) void prepass_kernel(PrepArgs a) {
    __shared__ int sbad;
    const int y = blockIdx.y;
    bool f32 = sniff_fp32(a.src[y], threadIdx.x, &sbad);
    if (!f32) return;   // bf16 inputs: planes unused downstream
    const int n8 = a.n8[y];
    for (int i = blockIdx.x*blockDim.x + threadIdx.x; i < n8; i += gridDim.x*blockDim.x)
        cvt8(a.hi[y] + (size_t)i*8, a.lo[y] + (size_t)i*8, (const float*)a.src[y] + (size_t)i*8);
}

// ================= Kernel 1: complex QKV projection =================
template<bool FP32>
__device__ __forceinline__ void qkv_epi(
    const void* fr_, const void* fi_, const void* bqr, const void* bqi,
    bf16* qr, bf16* qi, bf16* kr, bf16* ki, bf16* vr, bf16* vi,
    int row0, int col0,
    f32x4 (*accr)[2], f32x4 (*accs)[2], f32x4 (*acci)[2])
{
    const int t  = threadIdx.x;
    const int w  = t >> 6, l = t & 63;
    const int lr = l & 15, lg = l >> 4;
    const int wm = w >> 1, wn = w & 1;

    #pragma unroll
    for (int ni = 0; ni < 2; ++ni) {
        int col = col0 + wn*32 + ni*16 + lr;
        float bre = ldin<FP32>(bqr, col);
        float bim = ldin<FP32>(bqi, col);
        int s = col % 3;
        int tc = col / 3;
        int h = tc / HD, d = tc % HD;
        #pragma unroll
        for (int mi = 0; mi < 2; ++mi)
        #pragma unroll
        for (int r = 0; r < 4; ++r) {
            int row = row0 + wm*32 + mi*16 + 4*lg + r;
            int bb = row / N, n = row % N;
            float cr = accr[mi][ni][r] - accs[mi][ni][r] + bre;
            float ci = acci[mi][ni][r] + bim;
            if (s == 2) {
                int idxT = ((bb*HEADS + h)*HD + d)*N + n;   // V transposed [b,h,d,n]
                vr[idxT] = __float2bfloat16(scrub(cr));
                vi[idxT] = __float2bfloat16(scrub(ci));
            } else {
                float fre = ldin<FP32>(fr_, n*HD + d);
                float fim = ldin<FP32>(fi_, n*HD + d);
                float rr = cr*fre - ci*fim;
                float ri = cr*fim + ci*fre;
                int idx = ((bb*HEADS + h)*N + n)*HD + d;
                if (s == 0) { qr[idx] = __float2bfloat16(scrub(rr)); qi[idx] = __float2bfloat16(scrub(ri)); }
                else        { kr[idx] = __float2bfloat16(scrub(rr)); ki[idx] = __float2bfloat16(scrub(ri)); }
            }
        }
    }
}

// Traversal: COLUMNS partitioned across XCDs (XCD x owns col-tiles [6x,6x+6)),
// row-pair groups sweep inside: working set = 6 B-panels (3MB) + 2 A-panels
// (1MB) = 4MB -> fits per-XCD L2; B planes stay resident across the row sweep.
// Bijective: 8 xcd x 16 rtg x 6 ctl x 2 rtin = 1536.
template<int FM>   // 1 = pre-split planes, 2 = inline convert (ws fallback)
__global__ __launch_bounds__(256, 4) void qkv_kernel(
    const void* xr, const void* xi, const void* fr_, const void* fi_,
    const void* Wr, const void* Wi, const void* bqr, const void* bqi,
    const bf16* xrh, const bf16* xih, const bf16* xrl, const bf16* xil,
    const bf16* wrh, const bf16* wih, const bf16* wrl, const bf16* wil,
    bf16* qr, bf16* qi, bf16* kr, bf16* ki, bf16* vr, bf16* vi)
{
    __shared__ __align__(16) bf16 sA[4*PL], sB[4*PL];
    __shared__ int sbad;
    bool f32 = sniff_fp32(xr, threadIdx.x, &sbad);

    int wg   = blockIdx.x;
    int xcd  = wg & 7;
    int idx  = wg >> 3;          // 0..191
    int rtin = idx & 1;
    int tmp  = idx >> 1;         // 0..95
    int ctl  = tmp % 6;
    int rtg  = tmp / 6;          // 0..15
    int row0 = (rtg*2 + rtin) * 64;
    int col0 = (xcd*6 + ctl) * 64;

    f32x4 accr[2][2] = {}, accs[2][2] = {}, acci[2][2] = {};
    if (f32) {
        cgemm32<FM, FM>(xr, xi, xrh, xih, xrl, xil,
                        Wr, Wi, wrh, wih, wrl, wil,
                        row0, col0, sA, sB, accr, accs, acci);
        qkv_epi<true >(fr_, fi_, bqr, bqi, qr,qi,kr,ki,vr,vi, row0, col0, accr, accs, acci);
    } else {
        cgemm32<0, 0>(xr, xi, nullptr, nullptr, nullptr, nullptr,
                      Wr, Wi, nullptr, nullptr, nullptr, nullptr,
                      row0, col0, sA, sB, accr, accs, acci);
        qkv_epi<false>(fr_, fi_, bqr, bqi, qr,qi,kr,ki,vr,vi, row0, col0, accr, accs, acci);
    }
}

// ================= Kernel 2: flash-style MFMA attention (R4 verbatim) =================
__device__ __forceinline__ short8v frag_ld(const bf16* base, int row, int j) {
    return *(const short8v*)(base + row*64 + ((j ^ (row & 7)) << 3));
}

__global__ __launch_bounds__(256) void attn_kernel(
    const bf16* qr, const bf16* qi, const bf16* kr, const bf16* ki,
    const bf16* vtr, const bf16* vti, bf16* aor_, bf16* aoi_)
{
    __shared__ __align__(16) bf16 skr[64*64];
    __shared__ __align__(16) bf16 ski[64*64];
    __shared__ __align__(16) bf16 svr[64*64];   // Vt tile: [d][m]
    __shared__ __align__(16) bf16 svi[64*64];
    __shared__ __align__(16) bf16 sp[4][16*64]; // per-wave P tile

    const int t  = threadIdx.x;
    const int w  = t >> 6;
    const int l  = t & 63;
    const int lr = l & 15;
    const int lg = l >> 4;
    int wg = blockIdx.x;
    int sw = (wg & 7) * ((int)gridDim.x >> 3) + (wg >> 3);
    const int qt = sw & 15;
    const int bh = sw >> 4;

    const size_t hbase = (size_t)bh * N * HD;

    const bf16* qrg = qr + hbase + (size_t)(qt*64 + w*16 + lr) * HD;
    const bf16* qig = qi + hbase + (size_t)(qt*64 + w*16 + lr) * HD;
    short8v qfr[2], qfi[2], qfrn[2];
    #pragma unroll
    for (int ks = 0; ks < 2; ++ks) {
        qfr[ks] = *(const short8v*)(qrg + 32*ks + 8*lg);
        qfi[ks] = *(const short8v*)(qig + 32*ks + 8*lg);
        qfrn[ks] = neg8(qfr[ks]);
    }

    const int cA = t, cB = t + 256;
    const int rA = cA >> 3, jA = (cA & 7) ^ (rA & 7);
    const int rB = cB >> 3, jB = (cB & 7) ^ (rB & 7);
    const bf16* krg = kr  + hbase;
    const bf16* kig = ki  + hbase;
    const bf16* vrg = vtr + hbase;
    const bf16* vig = vti + hbase;

    f32x4 outr[4], outi[4];
    #pragma unroll
    for (int dt = 0; dt < 4; ++dt) {
        outr[dt] = (f32x4){0.f,0.f,0.f,0.f};
        outi[dt] = (f32x4){0.f,0.f,0.f,0.f};
    }
    float mrow[4] = {-1e30f,-1e30f,-1e30f,-1e30f};
    float lrow[4] = {0.f,0.f,0.f,0.f};

    for (int kt = 0; kt < N/64; ++kt) {
        const int m0 = kt*64;
        *(short8v*)(skr + cA*8) = *(const short8v*)(krg + (size_t)(m0+rA)*HD + jA*8);
        *(short8v*)(skr + cB*8) = *(const short8v*)(krg + (size_t)(m0+rB)*HD + jB*8);
        *(short8v*)(ski + cA*8) = *(const short8v*)(kig + (size_t)(m0+rA)*HD + jA*8);
        *(short8v*)(ski + cB*8) = *(const short8v*)(kig + (size_t)(m0+rB)*HD + jB*8);
        *(short8v*)(svr + cA*8) = *(const short8v*)(vrg + (size_t)rA*N + m0 + jA*8);
        *(short8v*)(svr + cB*8) = *(const short8v*)(vrg + (size_t)rB*N + m0 + jB*8);
        *(short8v*)(svi + cA*8) = *(const short8v*)(vig + (size_t)rA*N + m0 + jA*8);
        *(short8v*)(svi + cB*8) = *(const short8v*)(vig + (size_t)rB*N + m0 + jB*8);
        __syncthreads();

        f32x4 sr[4], si[4];
        #pragma unroll
        for (int ct = 0; ct < 4; ++ct) {
            f32x4 ar = (f32x4){0.f,0.f,0.f,0.f};
            f32x4 ai = (f32x4){0.f,0.f,0.f,0.f};
            #pragma unroll
            for (int ks = 0; ks < 2; ++ks) {
                short8v kfr = frag_ld(skr, 16*ct + lr, 4*ks + lg);
                short8v kfi = frag_ld(ski, 16*ct + lr, 4*ks + lg);
                ar = mfma16(qfr[ks],  kfr, ar);
                ar = mfma16(qfi[ks],  kfi, ar);
                ai = mfma16(qfi[ks],  kfr, ai);
                ai = mfma16(qfrn[ks], kfi, ai);
            }
            sr[ct] = ar; si[ct] = ai;
        }

        float p[4][4];
        float pmax[4] = {-1e30f,-1e30f,-1e30f,-1e30f};
        #pragma unroll
        for (int ct = 0; ct < 4; ++ct)
        #pragma unroll
        for (int r = 0; r < 4; ++r) {
            float s = sqrtf(sr[ct][r]*sr[ct][r] + si[ct][r]*si[ct][r]) * 0.125f;
            p[ct][r] = s;
            pmax[r] = fmaxf(pmax[r], s);
        }
        #pragma unroll
        for (int mk = 1; mk <= 8; mk <<= 1)
        #pragma unroll
        for (int r = 0; r < 4; ++r)
            pmax[r] = fmaxf(pmax[r], __shfl_xor(pmax[r], mk));

        float fsc[4];
        #pragma unroll
        for (int r = 0; r < 4; ++r) {
            float mnew = fmaxf(mrow[r], pmax[r]);
            fsc[r] = __expf(mrow[r] - mnew);
            mrow[r] = mnew;
        }
        float rsum[4] = {0.f,0.f,0.f,0.f};
        #pragma unroll
        for (int ct = 0; ct < 4; ++ct)
        #pragma unroll
        for (int r = 0; r < 4; ++r) {
            float e = __expf(p[ct][r] - mrow[r]);
            p[ct][r] = e;
            rsum[r] += e;
        }
        #pragma unroll
        for (int mk = 1; mk <= 8; mk <<= 1)
        #pragma unroll
        for (int r = 0; r < 4; ++r)
            rsum[r] += __shfl_xor(rsum[r], mk);
        #pragma unroll
        for (int r = 0; r < 4; ++r)
            lrow[r] = lrow[r]*fsc[r] + rsum[r];
        #pragma unroll
        for (int dt = 0; dt < 4; ++dt)
        #pragma unroll
        for (int r = 0; r < 4; ++r) {
            outr[dt][r] *= fsc[r];
            outi[dt][r] *= fsc[r];
        }

        bf16* pw = sp[w];
        #pragma unroll
        for (int ct = 0; ct < 4; ++ct)
        #pragma unroll
        for (int r = 0; r < 4; ++r) {
            int prow = 4*lg + r;
            int pcol = 16*ct + lr;
            int jj = (pcol >> 3) ^ (prow & 7);
            pw[prow*64 + jj*8 + (pcol & 7)] = __float2bfloat16(p[ct][r]);
        }
        short8v pa[2];
        #pragma unroll
        for (int ks2 = 0; ks2 < 2; ++ks2)
            pa[ks2] = frag_ld(pw, lr, 4*ks2 + lg);

        #pragma unroll
        for (int dt = 0; dt < 4; ++dt)
        #pragma unroll
        for (int ks2 = 0; ks2 < 2; ++ks2) {
            short8v vfr = frag_ld(svr, 16*dt + lr, 4*ks2 + lg);
            short8v vfi = frag_ld(svi, 16*dt + lr, 4*ks2 + lg);
            outr[dt] = mfma16(pa[ks2], vfr, outr[dt]);
            outi[dt] = mfma16(pa[ks2], vfi, outi[dt]);
        }
        __syncthreads();
    }

    const int b_ = bh / HEADS, h_ = bh % HEADS;
    float invl[4];
    #pragma unroll
    for (int r = 0; r < 4; ++r) invl[r] = 1.0f / lrow[r];
    #pragma unroll
    for (int dt = 0; dt < 4; ++dt)
    #pragma unroll
    for (int r = 0; r < 4; ++r) {
        int n_ = qt*64 + w*16 + 4*lg + r;
        int d_ = 16*dt + lr;
        size_t oidx = ((size_t)(b_*N + n_))*DIM + h_*HD + d_;
        aor_[oidx] = __float2bfloat16(scrub(outr[dt][r]*invl[r]));
        aoi_[oidx] = __float2bfloat16(scrub(outi[dt][r]*invl[r]));
    }
}

// ================= Kernel 3: complex out projection =================
// W as single bf16-hi plane (BMODE 3): 4 MFMA/pair. Error budget per R2
// measurement: one bf16 source ~ +0.068 in quadrature -> ~0.125 < 0.157.
template<int FM>   // 3 = single hi plane, 2 = inline fp32 split (ws fallback)
__global__ __launch_bounds__(256, 4) void outproj_kernel(
    const void* xprobe,
    const bf16* ar, const bf16* ai,
    const void* Wr, const void* Wi, const void* bor, const void* boi,
    const bf16* wrh, const bf16* wih,
    void* out)
{
    __shared__ __align__(16) bf16 sA[4*PL], sB[4*PL];
    __shared__ int sbad;
    bool f32 = sniff_fp32(xprobe, threadIdx.x, &sbad);

    // grid 512: 8 xcd x 16 rtg x 2 ctl x 2 rtin (bijective); cols across XCDs
    int wg   = blockIdx.x;
    int xcd  = wg & 7;
    int idx  = wg >> 3;          // 0..63
    int rtin = idx & 1;
    int tmp  = idx >> 1;         // 0..31
    int ctl  = tmp & 1;
    int rtg  = tmp >> 1;         // 0..15
    int row0 = (rtg*2 + rtin) * 64;
    int col0 = (xcd*2 + ctl) * 64;

    const int t  = threadIdx.x;
    const int w  = t >> 6, l = t & 63;
    const int lr = l & 15, lg = l >> 4;
    const int wm = w >> 1, wn = w & 1;

    f32x4 accr[2][2] = {}, accs[2][2] = {}, acci[2][2] = {};
    if (f32)
        cgemm32<0, FM>(ar, ai, nullptr, nullptr, nullptr, nullptr,
                       Wr, Wi, wrh, wih, nullptr, nullptr,
                       row0, col0, sA, sB, accr, accs, acci);
    else
        cgemm32<0, 0>(ar, ai, nullptr, nullptr, nullptr, nullptr,
                      Wr, Wi, nullptr, nullptr, nullptr, nullptr,
                      row0, col0, sA, sB, accr, accs, acci);

    #pragma unroll
    for (int ni = 0; ni < 2; ++ni) {
        int col = col0 + wn*32 + ni*16 + lr;
        float bre = f32 ? ldin<true>(bor, col) : ldin<false>(bor, col);
        float bim = f32 ? ldin<true>(boi, col) : ldin<false>(boi, col);
        #pragma unroll
        for (int mi = 0; mi < 2; ++mi)
        #pragma unroll
        for (int r = 0; r < 4; ++r) {
            int row = row0 + wm*32 + mi*16 + 4*lg + r;
            float cr = scrub(accr[mi][ni][r] - accs[mi][ni][r] + bre);
            float ci = scrub(acci[mi][ni][r] + bim);
            if (f32) {
                ((float*)out)[(size_t)row*DIM + col]                 = cr;
                ((float*)out)[(size_t)M*DIM + (size_t)row*DIM + col] = ci;
            } else {
                ((bf16*)out)[(size_t)row*DIM + col]                  = __float2bfloat16(cr);
                ((bf16*)out)[(size_t)M*DIM + (size_t)row*DIM + col]  = __float2bfloat16(ci);
            }
        }
    }
}

// ================= host =================
extern "C" void kernel_launch(void* const* d_in, const int* in_sizes, int n_in,
                              void* d_out, int out_size, void* d_ws, size_t ws_size,
                              hipStream_t stream)
{
    const void* xr     = d_in[0];
    const void* xi     = d_in[1];
    const void* fr     = d_in[2];
    const void* fi     = d_in[3];
    const void* Wqkv_r = d_in[4];
    const void* Wqkv_i = d_in[5];
    const void* bqkv_r = d_in[6];
    const void* bqkv_i = d_in[7];
    const void* Wout_r = d_in[8];
    const void* Wout_i = d_in[9];
    const void* bout_r = d_in[10];
    const void* bout_i = d_in[11];

    bf16* w = (bf16*)d_ws;
    const size_t QS  = (size_t)B*HEADS*N*HD;   // 2,097,152
    const size_t XS  = (size_t)M*DIM;          // 2,097,152
    const size_t WQS = (size_t)E3*DIM;         // 3,145,728
    const size_t WOS = (size_t)DIM*DIM;        // 1,048,576

    bf16* qr   = w;          bf16* qi   = qr  + QS;
    bf16* kr   = qi  + QS;   bf16* ki   = kr  + QS;
    bf16* vr   = ki  + QS;   bf16* vi   = vr  + QS;   // TRANSPOSED [b,h,d,n]
    bf16* aor_ = vi  + QS;   bf16* aoi_ = aor_ + QS;
    bf16* xrh = aoi_ + QS;   bf16* xih = xrh + XS;
    bf16* xrl = xih + XS;    bf16* xil = xrl + XS;
    bf16* wqrh = xil + XS;   bf16* wqih = wqrh + WQS;
    bf16* wqrl = wqih + WQS; bf16* wqil = wqrl + WQS;
    bf16* worh = wqil + WQS; bf16* woih = worh + WOS;
    bf16* worl = woih + WOS; bf16* woil = worl + WOS;

    const size_t need = (size_t)(8*QS + 4*XS + 4*WQS + 4*WOS) * sizeof(bf16);
    const bool pre = ws_size >= need;

    if (pre) {
        PrepArgs a;
        a.src[0] = xr;     a.hi[0] = xrh;  a.lo[0] = xrl;  a.n8[0] = (int)(XS/8);
        a.src[1] = xi;     a.hi[1] = xih;  a.lo[1] = xil;  a.n8[1] = (int)(XS/8);
        a.src[2] = Wqkv_r; a.hi[2] = wqrh; a.lo[2] = wqrl; a.n8[2] = (int)(WQS/8);
        a.src[3] = Wqkv_i; a.hi[3] = wqih; a.lo[3] = wqil; a.n8[3] = (int)(WQS/8);
        a.src[4] = Wout_r; a.hi[4] = worh; a.lo[4] = worl; a.n8[4] = (int)(WOS/8);
        a.src[5] = Wout_i; a.hi[5] = woih; a.lo[5] = woil; a.n8[5] = (int)(WOS/8);
        prepass_kernel<<<dim3(1536, 6), dim3(256), 0, stream>>>(a);

        qkv_kernel<1><<<dim3((E3/64)*(M/64)), dim3(256), 0, stream>>>(
            xr, xi, fr, fi, Wqkv_r, Wqkv_i, bqkv_r, bqkv_i,
            xrh, xih, xrl, xil, wqrh, wqih, wqrl, wqil,
            qr, qi, kr, ki, vr, vi);
    } else {
        qkv_kernel<2><<<dim3((E3/64)*(M/64)), dim3(256), 0, stream>>>(
            xr, xi, fr, fi, Wqkv_r, Wqkv_i, bqkv_r, bqkv_i,
            nullptr, nullptr, nullptr, nullptr, nullptr, nullptr, nullptr, nullptr,
            qr, qi, kr, ki, vr, vi);
    }

    attn_kernel<<<dim3(B*HEADS*(N/64)), dim3(256), 0, stream>>>(
        qr, qi, kr, ki, vr, vi, aor_, aoi_);

    if (pre) {
        outproj_kernel<3><<<dim3((DIM/64)*(M/64)), dim3(256), 0, stream>>>(
            xr, aor_, aoi_, Wout_r, Wout_i, bout_r, bout_i,
            worh, woih, d_out);
    } else {
        outproj_kernel<2><<<dim3((DIM/64)*(M/64)), dim3(256), 0, stream>>>(
            xr, aor_, aoi_, Wout_r, Wout_i, bout_r, bout_i,
            nullptr, nullptr, d_out);
    }
}

// Round 9
// 317.797 us; speedup vs baseline: 13.9864x; 1.1521x over previous
//
#include <hip/hip_runtime.h>
#include <hip/hip_bf16.h>
#include <stdint.h>

#define B 2
#define N 1024
#define DIM 1024
#define HEADS 16
#define HD 64
#define E3 (3*DIM)
#define M (B*N)

typedef __hip_bfloat16 bf16;
typedef __attribute__((ext_vector_type(8))) short short8v;
typedef __attribute__((ext_vector_type(4))) float f32x4;
typedef __attribute__((ext_vector_type(4))) unsigned int u32x4;

__device__ __forceinline__ float scrub(float v) {
    return (v == v && fabsf(v) < 1e30f) ? v : 0.0f;
}
__device__ __forceinline__ float b2f(bf16 x) { return scrub(__bfloat162float(x)); }

template<bool FP32>
__device__ __forceinline__ float ldin(const void* p, int i) {
    if (FP32) return scrub(((const float*)p)[i]);
    else      return scrub(__bfloat162float(((const bf16*)p)[i]));
}

__device__ __forceinline__ bool sniff_fp32(const void* x, int tid, int* sbad) {
    if (tid == 0) *sbad = 0;
    __syncthreads();
    if (tid < 64) {
        const unsigned short* u = (const unsigned short*)x;
        int ex = (u[tid] >> 7) & 0xFF;
        if (ex == 0xFF || ex >= 135 || (ex != 0 && ex <= 118))
            atomicAdd(sbad, 1);
    }
    __syncthreads();
    return *sbad > 4;
}

__device__ __forceinline__ short f2bs(float x) {
    bf16 h = __float2bfloat16(x);
    return __builtin_bit_cast(short, h);
}
__device__ __forceinline__ short8v neg8(short8v x) {   // flip bf16 sign bits
    u32x4 u = __builtin_bit_cast(u32x4, x);
    u ^= 0x80008000u;
    return __builtin_bit_cast(short8v, u);
}
__device__ __forceinline__ f32x4 mfma16(short8v a, short8v b, f32x4 c) {
    return __builtin_amdgcn_mfma_f32_16x16x32_bf16(a, b, c, 0, 0, 0);
}

// fp32x8 -> (hi, lo) bf16x8 split
__device__ __forceinline__ void cvt8(bf16* dhi, bf16* dlo, const float* s) {
    float4 a = *(const float4*)s;
    float4 b = *(const float4*)(s + 4);
    float v[8] = {a.x,a.y,a.z,a.w,b.x,b.y,b.z,b.w};
    short8v hi, lo;
    #pragma unroll
    for (int e = 0; e < 8; ++e) {
        float f = scrub(v[e]);
        bf16 h = __float2bfloat16(f);
        hi[e] = __builtin_bit_cast(short, h);
        lo[e] = f2bs(f - __bfloat162float(h));
    }
    *(short8v*)dhi = hi;
    *(short8v*)dlo = lo;
}
// fp32x8 -> hi bf16x8 only
__device__ __forceinline__ void cvt8h(bf16* dhi, const float* s) {
    float4 a = *(const float4*)s;
    float4 b = *(const float4*)(s + 4);
    float v[8] = {a.x,a.y,a.z,a.w,b.x,b.y,b.z,b.w};
    short8v hi;
    #pragma unroll
    for (int e = 0; e < 8; ++e)
        hi[e] = f2bs(scrub(v[e]));
    *(short8v*)dhi = hi;
}

// ================= LDS layout, BK=32 — R4-proven =================
#define PL (64*32)   // one plane: 64 rows x 32 bf16

__device__ __forceinline__ short8v frag_ld32(const bf16* base, int row, int j) {
    return *(const short8v*)(base + row*32 + ((j ^ (row & 3)) << 3));
}

// ================= complex bf16 MFMA GEMM core (R4-proven) =================
// C[row,col] = sum_k A[row,k]*W[col,k] (complex). Tile 64x64, BK=32.
// MODE: 0 = bf16 direct; 1 = pre-split hi/lo planes; 2 = fp32 inline convert;
//       3 = single bf16-hi plane (no lo terms).
// accr = Ar*Br terms, accs = Ai*Bi (subtract at epi), acci = imag.
template<int AMODE, int BMODE>
__device__ __forceinline__ void cgemm32(
    const void* Aor, const void* Aoi,
    const bf16* Arh, const bf16* Aih, const bf16* Arl, const bf16* Ail,
    const void* Bor, const void* Boi,
    const bf16* Brh, const bf16* Bih, const bf16* Brl, const bf16* Bil,
    int row0, int col0,
    bf16* sA, bf16* sB,
    f32x4 (*accr)[2], f32x4 (*accs)[2], f32x4 (*acci)[2])
{
    constexpr bool ALO = (AMODE == 1 || AMODE == 2);
    constexpr bool BLO = (BMODE == 1 || BMODE == 2);

    const int t  = threadIdx.x;
    const int w  = t >> 6, l = t & 63;
    const int lr = l & 15, lg = l >> 4;
    const int wm = w >> 1, wn = w & 1;

    const int srow = t >> 2;
    const int sj   = (t & 3) ^ (srow & 3);

    for (int k0 = 0; k0 < DIM; k0 += 32) {
        const size_t aoff = (size_t)(row0 + srow)*DIM + k0 + sj*8;
        const size_t boff = (size_t)(col0 + srow)*DIM + k0 + sj*8;
        bf16* dA = sA + t*8;
        bf16* dB = sB + t*8;
        if constexpr (AMODE == 0) {
            *(short8v*)(dA)        = *(const short8v*)((const bf16*)Aor + aoff);
            *(short8v*)(dA + PL)   = *(const short8v*)((const bf16*)Aoi + aoff);
        } else if constexpr (AMODE == 1) {
            *(short8v*)(dA)        = *(const short8v*)(Arh + aoff);
            *(short8v*)(dA + PL)   = *(const short8v*)(Aih + aoff);
            *(short8v*)(dA + 2*PL) = *(const short8v*)(Arl + aoff);
            *(short8v*)(dA + 3*PL) = *(const short8v*)(Ail + aoff);
        } else if constexpr (AMODE == 3) {
            *(short8v*)(dA)        = *(const short8v*)(Arh + aoff);
            *(short8v*)(dA + PL)   = *(const short8v*)(Aih + aoff);
        } else {
            cvt8(dA,      dA + 2*PL, (const float*)Aor + aoff);
            cvt8(dA + PL, dA + 3*PL, (const float*)Aoi + aoff);
        }
        if constexpr (BMODE == 0) {
            *(short8v*)(dB)        = *(const short8v*)((const bf16*)Bor + boff);
            *(short8v*)(dB + PL)   = *(const short8v*)((const bf16*)Boi + boff);
        } else if constexpr (BMODE == 1) {
            *(short8v*)(dB)        = *(const short8v*)(Brh + boff);
            *(short8v*)(dB + PL)   = *(const short8v*)(Bih + boff);
            *(short8v*)(dB + 2*PL) = *(const short8v*)(Brl + boff);
            *(short8v*)(dB + 3*PL) = *(const short8v*)(Bil + boff);
        } else if constexpr (BMODE == 3) {
            *(short8v*)(dB)        = *(const short8v*)(Brh + boff);
            *(short8v*)(dB + PL)   = *(const short8v*)(Bih + boff);
        } else {
            cvt8(dB,      dB + 2*PL, (const float*)Bor + boff);
            cvt8(dB + PL, dB + 3*PL, (const float*)Boi + boff);
        }
        __syncthreads();

        short8v arh[2], aih[2], arl[2], ail[2];
        #pragma unroll
        for (int mi = 0; mi < 2; ++mi) {
            int arow = wm*32 + mi*16 + lr;
            arh[mi] = frag_ld32(sA,      arow, lg);
            aih[mi] = frag_ld32(sA + PL, arow, lg);
            if constexpr (ALO) {
                arl[mi] = frag_ld32(sA + 2*PL, arow, lg);
                ail[mi] = frag_ld32(sA + 3*PL, arow, lg);
            }
        }
        #pragma unroll
        for (int ni = 0; ni < 2; ++ni) {
            int brow = wn*32 + ni*16 + lr;
            short8v brh = frag_ld32(sB,      brow, lg);
            short8v bih = frag_ld32(sB + PL, brow, lg);
            short8v brl, bil;
            if constexpr (BLO) {
                brl = frag_ld32(sB + 2*PL, brow, lg);
                bil = frag_ld32(sB + 3*PL, brow, lg);
            }
            #pragma unroll
            for (int mi = 0; mi < 2; ++mi) {
                accr[mi][ni] = mfma16(arh[mi], brh, accr[mi][ni]);
                accs[mi][ni] = mfma16(aih[mi], bih, accs[mi][ni]);
                acci[mi][ni] = mfma16(arh[mi], bih, acci[mi][ni]);
                acci[mi][ni] = mfma16(aih[mi], brh, acci[mi][ni]);
                if constexpr (BLO) {   // hi * lo
                    accr[mi][ni] = mfma16(arh[mi], brl, accr[mi][ni]);
                    accs[mi][ni] = mfma16(aih[mi], bil, accs[mi][ni]);
                    acci[mi][ni] = mfma16(arh[mi], bil, acci[mi][ni]);
                    acci[mi][ni] = mfma16(aih[mi], brl, acci[mi][ni]);
                }
                if constexpr (ALO) {   // lo * hi
                    accr[mi][ni] = mfma16(arl[mi], brh, accr[mi][ni]);
                    accs[mi][ni] = mfma16(ail[mi], bih, accs[mi][ni]);
                    acci[mi][ni] = mfma16(arl[mi], bih, acci[mi][ni]);
                    acci[mi][ni] = mfma16(ail[mi], brh, acci[mi][ni]);
                }
            }
        }
        __syncthreads();
    }
}

// ================= prepass: fp32 -> bf16 planes (hi/lo, or hi-only) =================
struct PrepArgs {
    const void* src[6];
    bf16* hi[6];
    bf16* lo[6];    // nullptr => hi-only
    int n8[6];
};

__global__ __launch_bounds__(256) void prepass_kernel(PrepArgs a) {
    __shared__ int sbad;
    const int y = blockIdx.y;
    bool f32 = sniff_fp32(a.src[y], threadIdx.x, &sbad);
    if (!f32) return;   // bf16 inputs: planes unused downstream
    const int n8 = a.n8[y];
    bf16* lo = a.lo[y];
    for (int i = blockIdx.x*blockDim.x + threadIdx.x; i < n8; i += gridDim.x*blockDim.x) {
        if (lo) cvt8 (a.hi[y] + (size_t)i*8, lo + (size_t)i*8, (const float*)a.src[y] + (size_t)i*8);
        else    cvt8h(a.hi[y] + (size_t)i*8,                   (const float*)a.src[y] + (size_t)i*8);
    }
}

// ================= Kernel 1: complex QKV projection =================
template<bool FP32>
__device__ __forceinline__ void qkv_epi(
    const void* fr_, const void* fi_, const void* bqr, const void* bqi,
    bf16* qr, bf16* qi, bf16* kr, bf16* ki, bf16* vr, bf16* vi,
    int row0, int col0,
    f32x4 (*accr)[2], f32x4 (*accs)[2], f32x4 (*acci)[2])
{
    const int t  = threadIdx.x;
    const int w  = t >> 6, l = t & 63;
    const int lr = l & 15, lg = l >> 4;
    const int wm = w >> 1, wn = w & 1;

    #pragma unroll
    for (int ni = 0; ni < 2; ++ni) {
        int col = col0 + wn*32 + ni*16 + lr;
        float bre = ldin<FP32>(bqr, col);
        float bim = ldin<FP32>(bqi, col);
        int s = col % 3;
        int tc = col / 3;
        int h = tc / HD, d = tc % HD;
        #pragma unroll
        for (int mi = 0; mi < 2; ++mi)
        #pragma unroll
        for (int r = 0; r < 4; ++r) {
            int row = row0 + wm*32 + mi*16 + 4*lg + r;
            int bb = row / N, n = row % N;
            float cr = accr[mi][ni][r] - accs[mi][ni][r] + bre;
            float ci = acci[mi][ni][r] + bim;
            if (s == 2) {
                int idxT = ((bb*HEADS + h)*HD + d)*N + n;   // V transposed [b,h,d,n]
                vr[idxT] = __float2bfloat16(scrub(cr));
                vi[idxT] = __float2bfloat16(scrub(ci));
            } else {
                float fre = ldin<FP32>(fr_, n*HD + d);
                float fim = ldin<FP32>(fi_, n*HD + d);
                float rr = cr*fre - ci*fim;
                float ri = cr*fim + ci*fre;
                int idx = ((bb*HEADS + h)*N + n)*HD + d;
                if (s == 0) { qr[idx] = __float2bfloat16(scrub(rr)); qi[idx] = __float2bfloat16(scrub(ri)); }
                else        { kr[idx] = __float2bfloat16(scrub(rr)); ki[idx] = __float2bfloat16(scrub(ri)); }
            }
        }
    }
}

// Traversal (R7-proven): cols across XCDs, row-pairs sweep inside.
// FM=1: x = hi/lo split planes (AMODE 1), W = hi-only plane (BMODE 3, 8 MFMA/pair).
// FM=2: inline fp32 split both sides (ws fallback).
template<int FM>
__global__ __launch_bounds__(256, 4) void qkv_kernel(
    const void* xr, const void* xi, const void* fr_, const void* fi_,
    const void* Wr, const void* Wi, const void* bqr, const void* bqi,
    const bf16* xrh, const bf16* xih, const bf16* xrl, const bf16* xil,
    const bf16* wrh, const bf16* wih,
    bf16* qr, bf16* qi, bf16* kr, bf16* ki, bf16* vr, bf16* vi)
{
    __shared__ __align__(16) bf16 sA[4*PL];
    __shared__ __align__(16) bf16 sB[(FM==1 ? 2 : 4)*PL];
    __shared__ int sbad;
    bool f32 = sniff_fp32(xr, threadIdx.x, &sbad);

    int wg   = blockIdx.x;
    int xcd  = wg & 7;
    int idx  = wg >> 3;          // 0..191
    int rtin = idx & 1;
    int tmp  = idx >> 1;         // 0..95
    int ctl  = tmp % 6;
    int rtg  = tmp / 6;          // 0..15
    int row0 = (rtg*2 + rtin) * 64;
    int col0 = (xcd*6 + ctl) * 64;

    f32x4 accr[2][2] = {}, accs[2][2] = {}, acci[2][2] = {};
    if (f32) {
        if constexpr (FM == 1)
            cgemm32<1, 3>(xr, xi, xrh, xih, xrl, xil,
                          Wr, Wi, wrh, wih, nullptr, nullptr,
                          row0, col0, sA, sB, accr, accs, acci);
        else
            cgemm32<2, 2>(xr, xi, nullptr, nullptr, nullptr, nullptr,
                          Wr, Wi, nullptr, nullptr, nullptr, nullptr,
                          row0, col0, sA, sB, accr, accs, acci);
        qkv_epi<true >(fr_, fi_, bqr, bqi, qr,qi,kr,ki,vr,vi, row0, col0, accr, accs, acci);
    } else {
        cgemm32<0, 0>(xr, xi, nullptr, nullptr, nullptr, nullptr,
                      Wr, Wi, nullptr, nullptr, nullptr, nullptr,
                      row0, col0, sA, sB, accr, accs, acci);
        qkv_epi<false>(fr_, fi_, bqr, bqi, qr,qi,kr,ki,vr,vi, row0, col0, accr, accs, acci);
    }
}

// ================= Kernel 2: flash-style MFMA attention (R4 verbatim) =================
__device__ __forceinline__ short8v frag_ld(const bf16* base, int row, int j) {
    return *(const short8v*)(base + row*64 + ((j ^ (row & 7)) << 3));
}

__global__ __launch_bounds__(256) void attn_kernel(
    const bf16* qr, const bf16* qi, const bf16* kr, const bf16* ki,
    const bf16* vtr, const bf16* vti, bf16* aor_, bf16* aoi_)
{
    __shared__ __align__(16) bf16 skr[64*64];
    __shared__ __align__(16) bf16 ski[64*64];
    __shared__ __align__(16) bf16 svr[64*64];   // Vt tile: [d][m]
    __shared__ __align__(16) bf16 svi[64*64];
    __shared__ __align__(16) bf16 sp[4][16*64]; // per-wave P tile

    const int t  = threadIdx.x;
    const int w  = t >> 6;
    const int l  = t & 63;
    const int lr = l & 15;
    const int lg = l >> 4;
    int wg = blockIdx.x;
    int sw = (wg & 7) * ((int)gridDim.x >> 3) + (wg >> 3);
    const int qt = sw & 15;
    const int bh = sw >> 4;

    const size_t hbase = (size_t)bh * N * HD;

    const bf16* qrg = qr + hbase + (size_t)(qt*64 + w*16 + lr) * HD;
    const bf16* qig = qi + hbase + (size_t)(qt*64 + w*16 + lr) * HD;
    short8v qfr[2], qfi[2], qfrn[2];
    #pragma unroll
    for (int ks = 0; ks < 2; ++ks) {
        qfr[ks] = *(const short8v*)(qrg + 32*ks + 8*lg);
        qfi[ks] = *(const short8v*)(qig + 32*ks + 8*lg);
        qfrn[ks] = neg8(qfr[ks]);
    }

    const int cA = t, cB = t + 256;
    const int rA = cA >> 3, jA = (cA & 7) ^ (rA & 7);
    const int rB = cB >> 3, jB = (cB & 7) ^ (rB & 7);
    const bf16* krg = kr  + hbase;
    const bf16* kig = ki  + hbase;
    const bf16* vrg = vtr + hbase;
    const bf16* vig = vti + hbase;

    f32x4 outr[4], outi[4];
    #pragma unroll
    for (int dt = 0; dt < 4; ++dt) {
        outr[dt] = (f32x4){0.f,0.f,0.f,0.f};
        outi[dt] = (f32x4){0.f,0.f,0.f,0.f};
    }
    float mrow[4] = {-1e30f,-1e30f,-1e30f,-1e30f};
    float lrow[4] = {0.f,0.f,0.f,0.f};

    for (int kt = 0; kt < N/64; ++kt) {
        const int m0 = kt*64;
        *(short8v*)(skr + cA*8) = *(const short8v*)(krg + (size_t)(m0+rA)*HD + jA*8);
        *(short8v*)(skr + cB*8) = *(const short8v*)(krg + (size_t)(m0+rB)*HD + jB*8);
        *(short8v*)(ski + cA*8) = *(const short8v*)(kig + (size_t)(m0+rA)*HD + jA*8);
        *(short8v*)(ski + cB*8) = *(const short8v*)(kig + (size_t)(m0+rB)*HD + jB*8);
        *(short8v*)(svr + cA*8) = *(const short8v*)(vrg + (size_t)rA*N + m0 + jA*8);
        *(short8v*)(svr + cB*8) = *(const short8v*)(vrg + (size_t)rB*N + m0 + jB*8);
        *(short8v*)(svi + cA*8) = *(const short8v*)(vig + (size_t)rA*N + m0 + jA*8);
        *(short8v*)(svi + cB*8) = *(const short8v*)(vig + (size_t)rB*N + m0 + jB*8);
        __syncthreads();

        f32x4 sr[4], si[4];
        #pragma unroll
        for (int ct = 0; ct < 4; ++ct) {
            f32x4 ar = (f32x4){0.f,0.f,0.f,0.f};
            f32x4 ai = (f32x4){0.f,0.f,0.f,0.f};
            #pragma unroll
            for (int ks = 0; ks < 2; ++ks) {
                short8v kfr = frag_ld(skr, 16*ct + lr, 4*ks + lg);
                short8v kfi = frag_ld(ski, 16*ct + lr, 4*ks + lg);
                ar = mfma16(qfr[ks],  kfr, ar);
                ar = mfma16(qfi[ks],  kfi, ar);
                ai = mfma16(qfi[ks],  kfr, ai);
                ai = mfma16(qfrn[ks], kfi, ai);
            }
            sr[ct] = ar; si[ct] = ai;
        }

        float p[4][4];
        float pmax[4] = {-1e30f,-1e30f,-1e30f,-1e30f};
        #pragma unroll
        for (int ct = 0; ct < 4; ++ct)
        #pragma unroll
        for (int r = 0; r < 4; ++r) {
            float s = sqrtf(sr[ct][r]*sr[ct][r] + si[ct][r]*si[ct][r]) * 0.125f;
            p[ct][r] = s;
            pmax[r] = fmaxf(pmax[r], s);
        }
        #pragma unroll
        for (int mk = 1; mk <= 8; mk <<= 1)
        #pragma unroll
        for (int r = 0; r < 4; ++r)
            pmax[r] = fmaxf(pmax[r], __shfl_xor(pmax[r], mk));

        float fsc[4];
        #pragma unroll
        for (int r = 0; r < 4; ++r) {
            float mnew = fmaxf(mrow[r], pmax[r]);
            fsc[r] = __expf(mrow[r] - mnew);
            mrow[r] = mnew;
        }
        float rsum[4] = {0.f,0.f,0.f,0.f};
        #pragma unroll
        for (int ct = 0; ct < 4; ++ct)
        #pragma unroll
        for (int r = 0; r < 4; ++r) {
            float e = __expf(p[ct][r] - mrow[r]);
            p[ct][r] = e;
            rsum[r] += e;
        }
        #pragma unroll
        for (int mk = 1; mk <= 8; mk <<= 1)
        #pragma unroll
        for (int r = 0; r < 4; ++r)
            rsum[r] += __shfl_xor(rsum[r], mk);
        #pragma unroll
        for (int r = 0; r < 4; ++r)
            lrow[r] = lrow[r]*fsc[r] + rsum[r];
        #pragma unroll
        for (int dt = 0; dt < 4; ++dt)
        #pragma unroll
        for (int r = 0; r < 4; ++r) {
            outr[dt][r] *= fsc[r];
            outi[dt][r] *= fsc[r];
        }

        bf16* pw = sp[w];
        #pragma unroll
        for (int ct = 0; ct < 4; ++ct)
        #pragma unroll
        for (int r = 0; r < 4; ++r) {
            int prow = 4*lg + r;
            int pcol = 16*ct + lr;
            int jj = (pcol >> 3) ^ (prow & 7);
            pw[prow*64 + jj*8 + (pcol & 7)] = __float2bfloat16(p[ct][r]);
        }
        short8v pa[2];
        #pragma unroll
        for (int ks2 = 0; ks2 < 2; ++ks2)
            pa[ks2] = frag_ld(pw, lr, 4*ks2 + lg);

        #pragma unroll
        for (int dt = 0; dt < 4; ++dt)
        #pragma unroll
        for (int ks2 = 0; ks2 < 2; ++ks2) {
            short8v vfr = frag_ld(svr, 16*dt + lr, 4*ks2 + lg);
            short8v vfi = frag_ld(svi, 16*dt + lr, 4*ks2 + lg);
            outr[dt] = mfma16(pa[ks2], vfr, outr[dt]);
            outi[dt] = mfma16(pa[ks2], vfi, outi[dt]);
        }
        __syncthreads();
    }

    const int b_ = bh / HEADS, h_ = bh % HEADS;
    float invl[4];
    #pragma unroll
    for (int r = 0; r < 4; ++r) invl[r] = 1.0f / lrow[r];
    #pragma unroll
    for (int dt = 0; dt < 4; ++dt)
    #pragma unroll
    for (int r = 0; r < 4; ++r) {
        int n_ = qt*64 + w*16 + 4*lg + r;
        int d_ = 16*dt + lr;
        size_t oidx = ((size_t)(b_*N + n_))*DIM + h_*HD + d_;
        aor_[oidx] = __float2bfloat16(scrub(outr[dt][r]*invl[r]));
        aoi_[oidx] = __float2bfloat16(scrub(outi[dt][r]*invl[r]));
    }
}

// ================= Kernel 3: complex out projection (R7-proven) =================
template<int FM>   // 3 = single hi plane, 2 = inline fp32 split (ws fallback)
__global__ __launch_bounds__(256, 4) void outproj_kernel(
    const void* xprobe,
    const bf16* ar, const bf16* ai,
    const void* Wr, const void* Wi, const void* bor, const void* boi,
    const bf16* wrh, const bf16* wih,
    void* out)
{
    __shared__ __align__(16) bf16 sA[2*PL];
    __shared__ __align__(16) bf16 sB[(FM==3 ? 2 : 4)*PL];
    __shared__ int sbad;
    bool f32 = sniff_fp32(xprobe, threadIdx.x, &sbad);

    // grid 512: 8 xcd x 16 rtg x 2 ctl x 2 rtin (bijective); cols across XCDs
    int wg   = blockIdx.x;
    int xcd  = wg & 7;
    int idx  = wg >> 3;          // 0..63
    int rtin = idx & 1;
    int tmp  = idx >> 1;         // 0..31
    int ctl  = tmp & 1;
    int rtg  = tmp >> 1;         // 0..15
    int row0 = (rtg*2 + rtin) * 64;
    int col0 = (xcd*2 + ctl) * 64;

    const int t  = threadIdx.x;
    const int w  = t >> 6, l = t & 63;
    const int lr = l & 15, lg = l >> 4;
    const int wm = w >> 1, wn = w & 1;

    f32x4 accr[2][2] = {}, accs[2][2] = {}, acci[2][2] = {};
    if (f32) {
        if constexpr (FM == 3)
            cgemm32<0, 3>(ar, ai, nullptr, nullptr, nullptr, nullptr,
                          Wr, Wi, wrh, wih, nullptr, nullptr,
                          row0, col0, sA, sB, accr, accs, acci);
        else
            cgemm32<0, 2>(ar, ai, nullptr, nullptr, nullptr, nullptr,
                          Wr, Wi, nullptr, nullptr, nullptr, nullptr,
                          row0, col0, sA, sB, accr, accs, acci);
    } else {
        cgemm32<0, 0>(ar, ai, nullptr, nullptr, nullptr, nullptr,
                      Wr, Wi, nullptr, nullptr, nullptr, nullptr,
                      row0, col0, sA, sB, accr, accs, acci);
    }

    #pragma unroll
    for (int ni = 0; ni < 2; ++ni) {
        int col = col0 + wn*32 + ni*16 + lr;
        float bre = f32 ? ldin<true>(bor, col) : ldin<false>(bor, col);
        float bim = f32 ? ldin<true>(boi, col) : ldin<false>(boi, col);
        #pragma unroll
        for (int mi = 0; mi < 2; ++mi)
        #pragma unroll
        for (int r = 0; r < 4; ++r) {
            int row = row0 + wm*32 + mi*16 + 4*lg + r;
            float cr = scrub(accr[mi][ni][r] - accs[mi][ni][r] + bre);
            float ci = scrub(acci[mi][ni][r] + bim);
            if (f32) {
                ((float*)out)[(size_t)row*DIM + col]                 = cr;
                ((float*)out)[(size_t)M*DIM + (size_t)row*DIM + col] = ci;
            } else {
                ((bf16*)out)[(size_t)row*DIM + col]                  = __float2bfloat16(cr);
                ((bf16*)out)[(size_t)M*DIM + (size_t)row*DIM + col]  = __float2bfloat16(ci);
            }
        }
    }
}

// ================= host =================
extern "C" void kernel_launch(void* const* d_in, const int* in_sizes, int n_in,
                              void* d_out, int out_size, void* d_ws, size_t ws_size,
                              hipStream_t stream)
{
    const void* xr     = d_in[0];
    const void* xi     = d_in[1];
    const void* fr     = d_in[2];
    const void* fi     = d_in[3];
    const void* Wqkv_r = d_in[4];
    const void* Wqkv_i = d_in[5];
    const void* bqkv_r = d_in[6];
    const void* bqkv_i = d_in[7];
    const void* Wout_r = d_in[8];
    const void* Wout_i = d_in[9];
    const void* bout_r = d_in[10];
    const void* bout_i = d_in[11];

    bf16* w = (bf16*)d_ws;
    const size_t QS  = (size_t)B*HEADS*N*HD;   // 2,097,152
    const size_t XS  = (size_t)M*DIM;          // 2,097,152
    const size_t WQS = (size_t)E3*DIM;         // 3,145,728
    const size_t WOS = (size_t)DIM*DIM;        // 1,048,576

    bf16* qr   = w;          bf16* qi   = qr  + QS;
    bf16* kr   = qi  + QS;   bf16* ki   = kr  + QS;
    bf16* vr   = ki  + QS;   bf16* vi   = vr  + QS;   // TRANSPOSED [b,h,d,n]
    bf16* aor_ = vi  + QS;   bf16* aoi_ = aor_ + QS;
    bf16* xrh = aoi_ + QS;   bf16* xih = xrh + XS;
    bf16* xrl = xih + XS;    bf16* xil = xrl + XS;
    bf16* wqrh = xil + XS;   bf16* wqih = wqrh + WQS;
    bf16* worh = wqih + WQS; bf16* woih = worh + WOS;

    const size_t need = (size_t)(8*QS + 4*XS + 2*WQS + 2*WOS) * sizeof(bf16);
    const bool pre = ws_size >= need;

    if (pre) {
        PrepArgs a;
        a.src[0] = xr;     a.hi[0] = xrh;  a.lo[0] = xrl;    a.n8[0] = (int)(XS/8);
        a.src[1] = xi;     a.hi[1] = xih;  a.lo[1] = xil;    a.n8[1] = (int)(XS/8);
        a.src[2] = Wqkv_r; a.hi[2] = wqrh; a.lo[2] = nullptr; a.n8[2] = (int)(WQS/8);
        a.src[3] = Wqkv_i; a.hi[3] = wqih; a.lo[3] = nullptr; a.n8[3] = (int)(WQS/8);
        a.src[4] = Wout_r; a.hi[4] = worh; a.lo[4] = nullptr; a.n8[4] = (int)(WOS/8);
        a.src[5] = Wout_i; a.hi[5] = woih; a.lo[5] = nullptr; a.n8[5] = (int)(WOS/8);
        prepass_kernel<<<dim3(1536, 6), dim3(256), 0, stream>>>(a);

        qkv_kernel<1><<<dim3((E3/64)*(M/64)), dim3(256), 0, stream>>>(
            xr, xi, fr, fi, Wqkv_r, Wqkv_i, bqkv_r, bqkv_i,
            xrh, xih, xrl, xil, wqrh, wqih,
            qr, qi, kr, ki, vr, vi);
    } else {
        qkv_kernel<2><<<dim3((E3/64)*(M/64)), dim3(256), 0, stream>>>(
            xr, xi, fr, fi, Wqkv_r, Wqkv_i, bqkv_r, bqkv_i,
            nullptr, nullptr, nullptr, nullptr, nullptr, nullptr,
            qr, qi, kr, ki, vr, vi);
    }

    attn_kernel<<<dim3(B*HEADS*(N/64)), dim3(256), 0, stream>>>(
        qr, qi, kr, ki, vr, vi, aor_, aoi_);

    if (pre) {
        outproj_kernel<3><<<dim3((DIM/64)*(M/64)), dim3(256), 0, stream>>>(
            xr, aor_, aoi_, Wout_r, Wout_i, bout_r, bout_i,
            worh, woih, d_out);
    } else {
        outproj_kernel<2><<<dim3((DIM/64)*(M/64)), dim3(256), 0, stream>>>(
            xr, aor_, aoi_, Wout_r, Wout_i, bout_r, bout_i,
            nullptr, nullptr, d_out);
    }
}